// Round 5
// baseline (285.624 us; speedup 1.0000x reference)
//
#include <hip/hip_runtime.h>
#include <hip/hip_bf16.h>

typedef __attribute__((ext_vector_type(8))) short s16x8;
typedef __attribute__((ext_vector_type(4))) float f32x4;

__device__ __forceinline__ unsigned short f2bfu(float x) {
  __hip_bfloat16 b = __float2bfloat16(x);
  return *reinterpret_cast<unsigned short*>(&b);
}
__device__ __forceinline__ short f2bfs(float x) { return (short)f2bfu(x); }

// ---------------- transpose + downcast: dst[C][R] = bf16(src[R][C]) ----------
__global__ __launch_bounds__(256) void transpose_k(const float* __restrict__ src,
                                                   unsigned short* __restrict__ dst,
                                                   int R, int C) {
  __shared__ float t[32][33];
  const int c0 = blockIdx.x * 32, r0 = blockIdx.y * 32;
  const int tx = threadIdx.x & 31, ty = threadIdx.x >> 5;
#pragma unroll
  for (int i = 0; i < 32; i += 8)
    t[ty + i][tx] = src[(size_t)(r0 + ty + i) * C + (c0 + tx)];
  __syncthreads();
#pragma unroll
  for (int i = 0; i < 32; i += 8)
    dst[(size_t)(c0 + ty + i) * R + (r0 + tx)] = f2bfu(t[tx][ty + i]);
}

// ---------------- xw_k: [V0 | QK] = X0 @ [Wv | Wq | Wk]  (f32 tiled GEMM) ----
// grid (10, 4): bn 0..7 -> Wv cols, 8 -> Wq, 9 -> Wk. M=256, K=512.
__global__ __launch_bounds__(256) void xw_k(const float* __restrict__ X0,
                                            const float* __restrict__ Wv,
                                            const float* __restrict__ Wq,
                                            const float* __restrict__ Wk,
                                            float* __restrict__ V0ws,
                                            float* __restrict__ QKws) {
  __shared__ float As[64][17];
  __shared__ float Bs[16][68];
  const int tid = threadIdx.x;
  const int bn = blockIdx.x, bm = blockIdx.y;
  const int tx = tid & 15, ty = tid >> 4;
  float acc[4][4] = {};
  for (int k0 = 0; k0 < 512; k0 += 16) {
    {
      const int row = tid & 63, kk = (tid >> 6) * 4;
      const float4 v = *reinterpret_cast<const float4*>(X0 + (size_t)(bm * 64 + row) * 512 + k0 + kk);
      As[row][kk] = v.x; As[row][kk + 1] = v.y; As[row][kk + 2] = v.z; As[row][kk + 3] = v.w;
    }
    {
      const int k = tid >> 4, n4 = (tid & 15) * 4;
      float4 v;
      if (bn < 8)       v = *reinterpret_cast<const float4*>(Wv + (size_t)(k0 + k) * 512 + bn * 64 + n4);
      else if (bn == 8) v = *reinterpret_cast<const float4*>(Wq + (size_t)(k0 + k) * 64 + n4);
      else              v = *reinterpret_cast<const float4*>(Wk + (size_t)(k0 + k) * 64 + n4);
      Bs[k][n4] = v.x; Bs[k][n4 + 1] = v.y; Bs[k][n4 + 2] = v.z; Bs[k][n4 + 3] = v.w;
    }
    __syncthreads();
#pragma unroll
    for (int kk = 0; kk < 16; ++kk) {
      float a[4], bb[4];
#pragma unroll
      for (int i = 0; i < 4; ++i) a[i] = As[ty * 4 + i][kk];
#pragma unroll
      for (int j = 0; j < 4; ++j) bb[j] = Bs[kk][tx * 4 + j];
#pragma unroll
      for (int i = 0; i < 4; ++i)
#pragma unroll
        for (int j = 0; j < 4; ++j) acc[i][j] = fmaf(a[i], bb[j], acc[i][j]);
    }
    __syncthreads();
  }
#pragma unroll
  for (int i = 0; i < 4; ++i) {
    const int row = bm * 64 + ty * 4 + i;
#pragma unroll
    for (int j = 0; j < 4; ++j) {
      const int n = tx * 4 + j;
      if (bn < 8)       V0ws[(size_t)row * 512 + bn * 64 + n] = acc[i][j];
      else if (bn == 8) QKws[(size_t)row * 128 + n] = acc[i][j];
      else              QKws[(size_t)row * 128 + 64 + n] = acc[i][j];
    }
  }
}

// ---------------- wsm_k: per-batch softmax weights w[256] ----------------
__global__ __launch_bounds__(256) void wsm_k(const float* __restrict__ Xs,
                                             const float* __restrict__ QKws,
                                             const float* __restrict__ bq,
                                             float* __restrict__ Wws) {
  const int b = blockIdx.x, t = threadIdx.x;
  __shared__ float sv[256];
  __shared__ float scal[4];
  sv[t] = (t == 0) ? 1.0f : Xs[b * 255 + t - 1];
  __syncthreads();
  if (t == 0) {
    float al = 0, g2 = 0;
    for (int j = 0; j < 64; ++j) {
      al = fmaf(QKws[b * 128 + j], QKws[b * 128 + 64 + j], al);
      g2 = fmaf(bq[j], QKws[b * 128 + 64 + j], g2);
    }
    float mx = sv[0], mn = sv[0];
    for (int m2 = 1; m2 < 256; ++m2) { mx = fmaxf(mx, sv[m2]); mn = fminf(mn, sv[m2]); }
    scal[0] = al; scal[1] = g2; scal[2] = mx; scal[3] = mn;
  }
  __syncthreads();
  const float c = fmaf(scal[0], sv[t], scal[1]);
  const float M = (c >= 0.f) ? c * scal[2] : c * scal[3];
  float Z = 0, Wm = 0;
  for (int m2 = 0; m2 < 256; ++m2) {
    const float e = __expf(fmaf(c, sv[m2], -M));
    Z += e;
    Wm = fmaf(sv[m2], e, Wm);
  }
  Wws[b * 256 + t] = Wm / Z;
}

// ---------------- prc_k: [P; R; Cpre] = [V0; X0; bv] @ W1  (f32 GEMM) --------
// grid (16, 9). M=513 (row 512 = bv), N=1024, K=512.
__global__ __launch_bounds__(256) void prc_k(const float* __restrict__ V0ws,
                                             const float* __restrict__ X0,
                                             const float* __restrict__ bv,
                                             const float* __restrict__ W1,
                                             const float* __restrict__ gp,
                                             const float* __restrict__ b1,
                                             float* __restrict__ Pws,
                                             float* __restrict__ Rws,
                                             float* __restrict__ Cws) {
  __shared__ float As[64][17];
  __shared__ float Bs[16][68];
  const int tid = threadIdx.x;
  const int bnx = blockIdx.x, bmy = blockIdx.y;
  const int tx = tid & 15, ty = tid >> 4;
  float acc[4][4] = {};
  for (int k0 = 0; k0 < 512; k0 += 16) {
    {
      const int row = tid & 63, kk = (tid >> 6) * 4;
      const int rowg = bmy * 64 + row;
      float4 v = {0.f, 0.f, 0.f, 0.f};
      if (rowg < 256)       v = *reinterpret_cast<const float4*>(V0ws + (size_t)rowg * 512 + k0 + kk);
      else if (rowg < 512)  v = *reinterpret_cast<const float4*>(X0 + (size_t)(rowg - 256) * 512 + k0 + kk);
      else if (rowg == 512) v = *reinterpret_cast<const float4*>(bv + k0 + kk);
      As[row][kk] = v.x; As[row][kk + 1] = v.y; As[row][kk + 2] = v.z; As[row][kk + 3] = v.w;
    }
    {
      const int k = tid >> 4, n4 = (tid & 15) * 4;
      const float4 v = *reinterpret_cast<const float4*>(W1 + (size_t)(k0 + k) * 1024 + bnx * 64 + n4);
      Bs[k][n4] = v.x; Bs[k][n4 + 1] = v.y; Bs[k][n4 + 2] = v.z; Bs[k][n4 + 3] = v.w;
    }
    __syncthreads();
#pragma unroll
    for (int kk = 0; kk < 16; ++kk) {
      float a[4], bb[4];
#pragma unroll
      for (int i = 0; i < 4; ++i) a[i] = As[ty * 4 + i][kk];
#pragma unroll
      for (int j = 0; j < 4; ++j) bb[j] = Bs[kk][tx * 4 + j];
#pragma unroll
      for (int i = 0; i < 4; ++i)
#pragma unroll
        for (int j = 0; j < 4; ++j) acc[i][j] = fmaf(a[i], bb[j], acc[i][j]);
    }
    __syncthreads();
  }
  const float g = gp[0];
#pragma unroll
  for (int i = 0; i < 4; ++i) {
    const int rowg = bmy * 64 + ty * 4 + i;
#pragma unroll
    for (int j = 0; j < 4; ++j) {
      const int col = bnx * 64 + tx * 4 + j;
      if (rowg < 256)       Pws[(size_t)rowg * 1024 + col] = acc[i][j];
      else if (rowg < 512)  Rws[(size_t)(rowg - 256) * 1024 + col] = acc[i][j];
      else if (rowg == 512) Cws[col] = fmaf(g, acc[i][j], b1[col]);
    }
  }
}

// ---------------- fused GEMM: out = relu(relu(h1@W2+b2)@W3 + b3) -------------
// BM=128, BN=512, BK=64, 512 thr (8 waves 2x4), wave tile 64x128.
// LDS bytes (140 KB total):
//   phase A: Bt dbuf 2x64KB [0,131072), PRC f32 12KB [131072,143360)
//            Bt layout: row n (0..511) at n*128B, 8 slots of 16B, slot s
//            stored at position s ^ (n&7)  (XOR swizzle, pre-swizzled DMA src)
//   phase B: h2t 64KB [0,65536) (row r at r*1024B, 64 slots, s^(r&7) swizzle),
//            W3 dbuf 2x16KB [65536,98304) (same format as Bt),
//            out f32 stage 32KB [98304,131072)
__global__ __launch_bounds__(512, 2) void fused_k(
    const float* __restrict__ Xs, const float* __restrict__ gp,
    const unsigned short* __restrict__ W2T,  // [512][1024] bf16
    const float* __restrict__ b2,
    const unsigned short* __restrict__ W3T,  // [128][512] bf16
    const float* __restrict__ b3,
    const float* __restrict__ Cws, const float* __restrict__ Wws,
    const float* __restrict__ Pws, const float* __restrict__ Rws,
    float* __restrict__ out)  // [65536][128] f32
{
  __shared__ __align__(16) unsigned char sm[143360];
  unsigned short* smU = (unsigned short*)sm;
  const int tid = threadIdx.x;
  const int lane = tid & 63;
  const int wid = tid >> 6;
  const int wr = wid >> 2, wc = wid & 3;
  const int la = lane & 15, q4 = lane >> 4;
  const int m0 = blockIdx.x * 128;
  const int b = m0 >> 8;
  const float g = gp[0];

  float gwm[4], srm[4];
#pragma unroll
  for (int m = 0; m < 4; ++m) {
    const int tok = (m0 & 255) + wr * 64 + m * 16 + la;
    gwm[m] = g * Wws[b * 256 + tok];
    srm[m] = (tok == 0) ? 1.0f : Xs[b * 255 + tok - 1];
  }

  // ---- PRC -> LDS (P @ +0, R @ +1024, C @ +2048 floats) ----
  {
    float* Pl = (float*)(sm + 131072);
#pragma unroll
    for (int i = 0; i < 6; ++i) {
      const int idx = i * 512 + tid;
      float v;
      if (idx < 1024)      v = Pws[b * 1024 + idx];
      else if (idx < 2048) v = Rws[b * 1024 + (idx - 1024)];
      else                 v = Cws[idx - 2048];
      Pl[idx] = v;
    }
  }

  // ---- B staging: 8 DMA/wave, each = 8 rows x one full 128B line ----
  auto stageA = [&](int buf, int k0) {
#pragma unroll
    for (int ii = 0; ii < 8; ++ii) {
      const int r0 = (wid * 8 + ii) * 8;
      const int row = r0 + (lane >> 3);
      const int s = (lane & 7) ^ (row & 7);
      const unsigned short* src = W2T + (size_t)row * 1024 + k0 + s * 8;
      __builtin_amdgcn_global_load_lds(
          (const __attribute__((address_space(1))) void*)src,
          (__attribute__((address_space(3))) void*)&sm[buf * 65536 + r0 * 128],
          16, 0, 0);
    }
  };

  f32x4 acc[4][8];
#pragma unroll
  for (int m = 0; m < 4; ++m)
#pragma unroll
    for (int nf = 0; nf < 8; ++nf) acc[m][nf] = (f32x4){0.f, 0.f, 0.f, 0.f};

  stageA(0, 0);
  __syncthreads();

  // ---- phase A: 16 K-steps of 64 ----
  const float* Pl = (const float*)(sm + 131072);
  for (int step = 0; step < 16; ++step) {
    const int cur = step & 1;
    if (step < 15) stageA(cur ^ 1, (step + 1) * 64);
#pragma unroll
    for (int ks2 = 0; ks2 < 2; ++ks2) {
      const int kb = step * 64 + ks2 * 32 + q4 * 8;
      const float4 P0 = *(const float4*)(Pl + kb);
      const float4 P1 = *(const float4*)(Pl + kb + 4);
      const float4 R0 = *(const float4*)(Pl + 1024 + kb);
      const float4 R1 = *(const float4*)(Pl + 1024 + kb + 4);
      const float4 C0 = *(const float4*)(Pl + 2048 + kb);
      const float4 C1 = *(const float4*)(Pl + 2048 + kb + 4);
      s16x8 af[4];
#pragma unroll
      for (int m = 0; m < 4; ++m) {
        const float gw = gwm[m], sr = srm[m];
        s16x8 v;
        v[0] = f2bfs(fmaxf(fmaf(gw, P0.x, fmaf(sr, R0.x, C0.x)), 0.f));
        v[1] = f2bfs(fmaxf(fmaf(gw, P0.y, fmaf(sr, R0.y, C0.y)), 0.f));
        v[2] = f2bfs(fmaxf(fmaf(gw, P0.z, fmaf(sr, R0.z, C0.z)), 0.f));
        v[3] = f2bfs(fmaxf(fmaf(gw, P0.w, fmaf(sr, R0.w, C0.w)), 0.f));
        v[4] = f2bfs(fmaxf(fmaf(gw, P1.x, fmaf(sr, R1.x, C1.x)), 0.f));
        v[5] = f2bfs(fmaxf(fmaf(gw, P1.y, fmaf(sr, R1.y, C1.y)), 0.f));
        v[6] = f2bfs(fmaxf(fmaf(gw, P1.z, fmaf(sr, R1.z, C1.z)), 0.f));
        v[7] = f2bfs(fmaxf(fmaf(gw, P1.w, fmaf(sr, R1.w, C1.w)), 0.f));
        af[m] = v;
      }
#pragma unroll
      for (int nf = 0; nf < 8; ++nf) {
        const int n = wc * 128 + nf * 16 + la;
        const int sl = (ks2 * 4 + q4) ^ (n & 7);
        const s16x8 bfr = *(const s16x8*)(sm + cur * 65536 + n * 128 + sl * 16);
#pragma unroll
        for (int m = 0; m < 4; ++m)
          acc[m][nf] = __builtin_amdgcn_mfma_f32_16x16x32_bf16(af[m], bfr, acc[m][nf], 0, 0, 0);
      }
    }
    __syncthreads();
  }

  // ---- W3 staging (same line-aligned DMA format) ----
  auto stageW3 = [&](int buf, int kc) {
#pragma unroll
    for (int ii = 0; ii < 2; ++ii) {
      const int r0 = (wid * 2 + ii) * 8;
      const int n = r0 + (lane >> 3);
      const int s = (lane & 7) ^ (n & 7);
      const unsigned short* src = W3T + (size_t)n * 512 + kc * 64 + s * 8;
      __builtin_amdgcn_global_load_lds(
          (const __attribute__((address_space(1))) void*)src,
          (__attribute__((address_space(3))) void*)&sm[65536 + buf * 16384 + r0 * 128],
          16, 0, 0);
    }
  };

  // ---- phase B: two 64-row halves ----
  for (int h = 0; h < 2; ++h) {
    __syncthreads();
    if (wr == h) {
#pragma unroll
      for (int nf = 0; nf < 8; ++nf) {
        const int col = wc * 128 + nf * 16 + la;  // phase-B k index
        const float bb = b2[col];
        const int sc = col >> 3, c7 = col & 7;
#pragma unroll
        for (int m = 0; m < 4; ++m) {
          const int rl = m * 16 + q4 * 4;
#pragma unroll
          for (int qq = 0; qq < 4; ++qq) {
            const int r = rl + qq;
            smU[r * 512 + ((sc ^ (r & 7)) << 3) + c7] =
                f2bfu(fmaxf(acc[m][nf][qq] + bb, 0.f));
          }
        }
      }
    }
    stageW3(0, 0);
    __syncthreads();

    f32x4 acc2[2][2];
#pragma unroll
    for (int mi = 0; mi < 2; ++mi)
#pragma unroll
      for (int ni = 0; ni < 2; ++ni) acc2[mi][ni] = (f32x4){0.f, 0.f, 0.f, 0.f};

    for (int kc = 0; kc < 8; ++kc) {
      const int wbuf = kc & 1;
      if (kc < 7) stageW3(wbuf ^ 1, kc + 1);
#pragma unroll
      for (int k2 = 0; k2 < 2; ++k2) {
        s16x8 af2[2], bf2[2];
#pragma unroll
        for (int mi = 0; mi < 2; ++mi) {
          const int r = wr * 32 + mi * 16 + la;
          const int sK = kc * 8 + k2 * 4 + q4;
          af2[mi] = *(const s16x8*)(sm + r * 1024 + ((sK ^ (r & 7)) << 4));
        }
#pragma unroll
        for (int ni = 0; ni < 2; ++ni) {
          const int n = wc * 32 + ni * 16 + la;
          const int sl = (k2 * 4 + q4) ^ (n & 7);
          bf2[ni] = *(const s16x8*)(sm + 65536 + wbuf * 16384 + n * 128 + sl * 16);
        }
#pragma unroll
        for (int mi = 0; mi < 2; ++mi)
#pragma unroll
          for (int ni = 0; ni < 2; ++ni)
            acc2[mi][ni] = __builtin_amdgcn_mfma_f32_16x16x32_bf16(af2[mi], bf2[ni], acc2[mi][ni], 0, 0, 0);
      }
      __syncthreads();
    }

    // epilogue: acc2 -> f32 LDS stage -> coalesced float4 row writes
    float* ost = (float*)(sm + 98304);
#pragma unroll
    for (int ni = 0; ni < 2; ++ni) {
      const int col = wc * 32 + ni * 16 + la;
      const float bb = b3[col];
#pragma unroll
      for (int mi = 0; mi < 2; ++mi) {
        const int rl = wr * 32 + mi * 16 + q4 * 4;
#pragma unroll
        for (int qq = 0; qq < 4; ++qq)
          ost[(rl + qq) * 128 + col] = fmaxf(acc2[mi][ni][qq] + bb, 0.f);
      }
    }
    __syncthreads();
#pragma unroll
    for (int i = 0; i < 4; ++i) {
      const int flat = i * 512 + tid;          // float4 units
      const int r = flat >> 5, gc = flat & 31;
      const float4 v = *(const float4*)(ost + r * 128 + gc * 4);
      *(float4*)(out + (size_t)(m0 + h * 64 + r) * 128 + gc * 4) = v;
    }
  }
}

extern "C" void kernel_launch(void* const* d_in, const int* in_sizes, int n_in,
                              void* d_out, int out_size, void* d_ws, size_t ws_size,
                              hipStream_t stream) {
  const float* X0 = (const float*)d_in[0];
  const float* Xs = (const float*)d_in[1];
  const float* Wq = (const float*)d_in[2];
  const float* bq = (const float*)d_in[3];
  const float* Wk = (const float*)d_in[4];
  const float* bk = (const float*)d_in[5];
  const float* Wv = (const float*)d_in[6];
  const float* bv = (const float*)d_in[7];
  const float* gp = (const float*)d_in[8];
  const float* W1 = (const float*)d_in[9];
  const float* b1 = (const float*)d_in[10];
  const float* W2 = (const float*)d_in[11];
  const float* b2 = (const float*)d_in[12];
  const float* W3 = (const float*)d_in[13];
  const float* b3 = (const float*)d_in[14];

  char* ws = (char*)d_ws;
  float* Cws = (float*)(ws);                              //   4 KB
  float* Wws = (float*)(ws + 4096);                       // 256 KB
  float* Pws = (float*)(ws + 266240);                     //   1 MB
  float* Rws = (float*)(ws + 1314816);                    //   1 MB
  unsigned short* W2T = (unsigned short*)(ws + 2363392);  //   1 MB (bf16)
  unsigned short* W3T = (unsigned short*)(ws + 3411968);  // 128 KB (bf16)
  float* V0ws = (float*)(ws + 3543040);                   // 512 KB
  float* QKws = (float*)(ws + 4067328);                   // 128 KB
  float* out = (float*)d_out;

  hipLaunchKernelGGL(transpose_k, dim3(16, 32), dim3(256), 0, stream, W2, W2T, 1024, 512);
  hipLaunchKernelGGL(transpose_k, dim3(4, 16), dim3(256), 0, stream, W3, W3T, 512, 128);
  hipLaunchKernelGGL(xw_k, dim3(10, 4), dim3(256), 0, stream, X0, Wv, Wq, Wk, V0ws, QKws);
  hipLaunchKernelGGL(wsm_k, dim3(256), dim3(256), 0, stream, Xs, QKws, bq, Wws);
  hipLaunchKernelGGL(prc_k, dim3(16, 9), dim3(256), 0, stream, V0ws, X0, bv, W1, gp, b1, Pws, Rws, Cws);
  hipLaunchKernelGGL(fused_k, dim3(512), dim3(512), 0, stream,
                     Xs, gp, W2T, b2, W3T, b3, Cws, Wws, Pws, Rws, out);
}

// Round 6
// 214.967 us; speedup vs baseline: 1.3287x; 1.3287x over previous
//
#include <hip/hip_runtime.h>
#include <hip/hip_bf16.h>

typedef __attribute__((ext_vector_type(8))) short s16x8;
typedef __attribute__((ext_vector_type(4))) short s16x4;
typedef __attribute__((ext_vector_type(4))) float f32x4;

__device__ __forceinline__ unsigned short f2bfu(float x) {
  __hip_bfloat16 b = __float2bfloat16(x);
  return *reinterpret_cast<unsigned short*>(&b);
}
__device__ __forceinline__ short f2bfs(float x) { return (short)f2bfu(x); }

// -------- merged transpose + downcast: W2T[512][1024], W3T[128][512] --------
__global__ __launch_bounds__(256) void transpose_all_k(
    const float* __restrict__ W2, const float* __restrict__ W3,
    unsigned short* __restrict__ W2T, unsigned short* __restrict__ W3T) {
  __shared__ float t[32][33];
  int blk = blockIdx.x;
  const float* src;
  unsigned short* dst;
  int R, C, bx, by;
  if (blk < 512) { src = W2; dst = W2T; R = 1024; C = 512; bx = blk & 15; by = blk >> 4; }
  else { blk -= 512; src = W3; dst = W3T; R = 512; C = 128; bx = blk & 3; by = blk >> 2; }
  const int c0 = bx * 32, r0 = by * 32;
  const int tx = threadIdx.x & 31, ty = threadIdx.x >> 5;
#pragma unroll
  for (int i = 0; i < 32; i += 8)
    t[ty + i][tx] = src[(size_t)(r0 + ty + i) * C + (c0 + tx)];
  __syncthreads();
#pragma unroll
  for (int i = 0; i < 32; i += 8)
    dst[(size_t)(c0 + ty + i) * R + (r0 + tx)] = f2bfu(t[tx][ty + i]);
}

// -------- xw_k: [V0 | QK] = X0 @ [Wv | Wq | Wk], 32x64 tiles, grid (10,8) ----
__global__ __launch_bounds__(256) void xw_k(const float* __restrict__ X0,
                                            const float* __restrict__ Wv,
                                            const float* __restrict__ Wq,
                                            const float* __restrict__ Wk,
                                            float* __restrict__ V0ws,
                                            float* __restrict__ QKws) {
  __shared__ float As[32][17];
  __shared__ float Bs[16][68];
  const int tid = threadIdx.x;
  const int bn = blockIdx.x, bm = blockIdx.y;
  const int tx = tid & 15, ty = tid >> 4;
  float acc[2][4] = {};
  for (int k0 = 0; k0 < 512; k0 += 16) {
    if (tid < 128) {
      const int row = tid >> 2, kk = (tid & 3) * 4;
      const float4 v = *reinterpret_cast<const float4*>(X0 + (size_t)(bm * 32 + row) * 512 + k0 + kk);
      As[row][kk] = v.x; As[row][kk + 1] = v.y; As[row][kk + 2] = v.z; As[row][kk + 3] = v.w;
    }
    {
      const int k = tid >> 4, n4 = (tid & 15) * 4;
      float4 v;
      if (bn < 8)       v = *reinterpret_cast<const float4*>(Wv + (size_t)(k0 + k) * 512 + bn * 64 + n4);
      else if (bn == 8) v = *reinterpret_cast<const float4*>(Wq + (size_t)(k0 + k) * 64 + n4);
      else              v = *reinterpret_cast<const float4*>(Wk + (size_t)(k0 + k) * 64 + n4);
      Bs[k][n4] = v.x; Bs[k][n4 + 1] = v.y; Bs[k][n4 + 2] = v.z; Bs[k][n4 + 3] = v.w;
    }
    __syncthreads();
#pragma unroll
    for (int kk = 0; kk < 16; ++kk) {
      float a[2], bb[4];
#pragma unroll
      for (int i = 0; i < 2; ++i) a[i] = As[ty * 2 + i][kk];
#pragma unroll
      for (int j = 0; j < 4; ++j) bb[j] = Bs[kk][tx * 4 + j];
#pragma unroll
      for (int i = 0; i < 2; ++i)
#pragma unroll
        for (int j = 0; j < 4; ++j) acc[i][j] = fmaf(a[i], bb[j], acc[i][j]);
    }
    __syncthreads();
  }
#pragma unroll
  for (int i = 0; i < 2; ++i) {
    const int row = bm * 32 + ty * 2 + i;
#pragma unroll
    for (int j = 0; j < 4; ++j) {
      const int n = tx * 4 + j;
      if (bn < 8)       V0ws[(size_t)row * 512 + bn * 64 + n] = acc[i][j];
      else if (bn == 8) QKws[(size_t)row * 128 + n] = acc[i][j];
      else              QKws[(size_t)row * 128 + 64 + n] = acc[i][j];
    }
  }
}

// -------- wsm_k: per-batch softmax weights w[256] --------
__global__ __launch_bounds__(256) void wsm_k(const float* __restrict__ Xs,
                                             const float* __restrict__ QKws,
                                             const float* __restrict__ bq,
                                             float* __restrict__ Wws) {
  const int b = blockIdx.x, t = threadIdx.x;
  __shared__ float sv[256];
  __shared__ float scal[4];
  sv[t] = (t == 0) ? 1.0f : Xs[b * 255 + t - 1];
  __syncthreads();
  if (t == 0) {
    float al = 0, g2 = 0;
    for (int j = 0; j < 64; ++j) {
      al = fmaf(QKws[b * 128 + j], QKws[b * 128 + 64 + j], al);
      g2 = fmaf(bq[j], QKws[b * 128 + 64 + j], g2);
    }
    float mx = sv[0], mn = sv[0];
    for (int m2 = 1; m2 < 256; ++m2) { mx = fmaxf(mx, sv[m2]); mn = fminf(mn, sv[m2]); }
    scal[0] = al; scal[1] = g2; scal[2] = mx; scal[3] = mn;
  }
  __syncthreads();
  const float c = fmaf(scal[0], sv[t], scal[1]);
  const float M = (c >= 0.f) ? c * scal[2] : c * scal[3];
  float Z = 0, Wm = 0;
  for (int m2 = 0; m2 < 256; ++m2) {
    const float e = __expf(fmaf(c, sv[m2], -M));
    Z += e;
    Wm = fmaf(sv[m2], e, Wm);
  }
  Wws[b * 256 + t] = Wm / Z;
}

// -------- prc_k: [P; R; Cpre] = [V0; X0; bv] @ W1, 32x64 tiles, grid (16,17) -
__global__ __launch_bounds__(256) void prc_k(const float* __restrict__ V0ws,
                                             const float* __restrict__ X0,
                                             const float* __restrict__ bv,
                                             const float* __restrict__ W1,
                                             const float* __restrict__ gp,
                                             const float* __restrict__ b1,
                                             float* __restrict__ Pws,
                                             float* __restrict__ Rws,
                                             float* __restrict__ Cws) {
  __shared__ float As[32][17];
  __shared__ float Bs[16][68];
  const int tid = threadIdx.x;
  const int bnx = blockIdx.x, bmy = blockIdx.y;
  const int tx = tid & 15, ty = tid >> 4;
  float acc[2][4] = {};
  for (int k0 = 0; k0 < 512; k0 += 16) {
    if (tid < 128) {
      const int row = tid >> 2, kk = (tid & 3) * 4;
      const int rowg = bmy * 32 + row;
      float4 v = {0.f, 0.f, 0.f, 0.f};
      if (rowg < 256)       v = *reinterpret_cast<const float4*>(V0ws + (size_t)rowg * 512 + k0 + kk);
      else if (rowg < 512)  v = *reinterpret_cast<const float4*>(X0 + (size_t)(rowg - 256) * 512 + k0 + kk);
      else if (rowg == 512) v = *reinterpret_cast<const float4*>(bv + k0 + kk);
      As[row][kk] = v.x; As[row][kk + 1] = v.y; As[row][kk + 2] = v.z; As[row][kk + 3] = v.w;
    }
    {
      const int k = tid >> 4, n4 = (tid & 15) * 4;
      const float4 v = *reinterpret_cast<const float4*>(W1 + (size_t)(k0 + k) * 1024 + bnx * 64 + n4);
      Bs[k][n4] = v.x; Bs[k][n4 + 1] = v.y; Bs[k][n4 + 2] = v.z; Bs[k][n4 + 3] = v.w;
    }
    __syncthreads();
#pragma unroll
    for (int kk = 0; kk < 16; ++kk) {
      float a[2], bb[4];
#pragma unroll
      for (int i = 0; i < 2; ++i) a[i] = As[ty * 2 + i][kk];
#pragma unroll
      for (int j = 0; j < 4; ++j) bb[j] = Bs[kk][tx * 4 + j];
#pragma unroll
      for (int i = 0; i < 2; ++i)
#pragma unroll
        for (int j = 0; j < 4; ++j) acc[i][j] = fmaf(a[i], bb[j], acc[i][j]);
    }
    __syncthreads();
  }
  const float g = gp[0];
#pragma unroll
  for (int i = 0; i < 2; ++i) {
    const int rowg = bmy * 32 + ty * 2 + i;
#pragma unroll
    for (int j = 0; j < 4; ++j) {
      const int col = bnx * 64 + tx * 4 + j;
      if (rowg < 256)       Pws[(size_t)rowg * 1024 + col] = acc[i][j];
      else if (rowg < 512)  Rws[(size_t)(rowg - 256) * 1024 + col] = acc[i][j];
      else if (rowg == 512) Cws[col] = fmaf(g, acc[i][j], b1[col]);
    }
  }
}

// -------- fused: out = relu(relu(h1@W2+b2)@W3 + b3) --------
// BM=64, BN=512, BK=64, 1024 thr (16 waves 2x8, 4 waves/SIMD), grid 1024.
// LDS (144 KB):
//   Bt dbuf 2x64KB [0,131072): row n at n*128B, slot p holds k-slot p^(n&7)
//   At dbuf 2x8KB [131072,147456): [ks 0..7][row 0..63][16B]
//   phase B reuse: h2t [0,65536): row r at r*1024B, slot swz=(s&56)|((s^r)&7)
//                  ost f32 stride-132 at [65536, 99328)
__global__ __launch_bounds__(1024, 4) void fused_k(
    const float* __restrict__ Xs, const float* __restrict__ gp,
    const unsigned short* __restrict__ W2T,  // [512][1024] bf16
    const float* __restrict__ b2,
    const unsigned short* __restrict__ W3T,  // [128][512] bf16
    const float* __restrict__ b3,
    const float* __restrict__ Cws, const float* __restrict__ Wws,
    const float* __restrict__ Pws, const float* __restrict__ Rws,
    float* __restrict__ out)  // [65536][128] f32
{
  __shared__ __align__(16) unsigned char sm[147456];
  unsigned short* smU = (unsigned short*)sm;
  const int tid = threadIdx.x;
  const int lane = tid & 63, wid = tid >> 6;  // 16 waves
  const int la = lane & 15, q4 = lane >> 4;
  const int wr = wid >> 3, wc = wid & 7;      // 2 x 8
  const int m0 = blockIdx.x * 64;
  const int b = blockIdx.x >> 2;
  const float g = gp[0];

  // A-gen assignment: thread -> (row ra, k-quad kq), 4 elems each
  const int ra = tid & 63, kq = tid >> 6;  // kq 0..15
  const int tok = (m0 & 255) + ra;
  const float gw = g * Wws[b * 256 + tok];
  const float sr = (tok == 0) ? 1.0f : Xs[b * 255 + tok - 1];
  const float* Pp = Pws + b * 1024;
  const float* Rp = Rws + b * 1024;

  auto agen_write = [&](int buf, int k0) {
    const int kg = k0 + kq * 4;
    const float4 Pv = *reinterpret_cast<const float4*>(Pp + kg);
    const float4 Rv = *reinterpret_cast<const float4*>(Rp + kg);
    const float4 Cv = *reinterpret_cast<const float4*>(Cws + kg);
    s16x4 v;
    v[0] = f2bfs(fmaxf(fmaf(gw, Pv.x, fmaf(sr, Rv.x, Cv.x)), 0.f));
    v[1] = f2bfs(fmaxf(fmaf(gw, Pv.y, fmaf(sr, Rv.y, Cv.y)), 0.f));
    v[2] = f2bfs(fmaxf(fmaf(gw, Pv.z, fmaf(sr, Rv.z, Cv.z)), 0.f));
    v[3] = f2bfs(fmaxf(fmaf(gw, Pv.w, fmaf(sr, Rv.w, Cv.w)), 0.f));
    *reinterpret_cast<s16x4*>(&sm[131072 + buf * 8192 + (kq >> 1) * 1024 + ra * 16 + (kq & 1) * 8]) = v;
  };

  auto stageB = [&](int buf, int k0) {
#pragma unroll
    for (int ii = 0; ii < 4; ++ii) {
      const int r0 = (wid * 4 + ii) * 8;
      const int row = r0 + (lane >> 3);
      const int sl = (lane & 7) ^ (row & 7);
      const unsigned short* src = W2T + (size_t)row * 1024 + k0 + sl * 8;
      __builtin_amdgcn_global_load_lds(
          (const __attribute__((address_space(1))) void*)src,
          (__attribute__((address_space(3))) void*)&sm[buf * 65536 + r0 * 128],
          16, 0, 0);
    }
  };

  f32x4 acc[2][4];
#pragma unroll
  for (int m = 0; m < 2; ++m)
#pragma unroll
    for (int nf = 0; nf < 4; ++nf) acc[m][nf] = (f32x4){0.f, 0.f, 0.f, 0.f};

  stageB(0, 0);
  agen_write(0, 0);
  __syncthreads();

  // ---- phase A: 16 K-steps of 64 ----
  for (int step = 0; step < 16; ++step) {
    const int cur = step & 1;
    if (step < 15) {
      stageB(cur ^ 1, (step + 1) * 64);
      agen_write(cur ^ 1, (step + 1) * 64);
    }
#pragma unroll
    for (int kk = 0; kk < 2; ++kk) {
      const int s = kk * 4 + q4;  // k-slot 0..7
      s16x8 af[2], bfr[4];
#pragma unroll
      for (int m = 0; m < 2; ++m)
        af[m] = *reinterpret_cast<const s16x8*>(
            &sm[131072 + cur * 8192 + s * 1024 + (wr * 32 + m * 16 + la) * 16]);
#pragma unroll
      for (int nf = 0; nf < 4; ++nf) {
        const int n = wc * 64 + nf * 16 + la;
        bfr[nf] = *reinterpret_cast<const s16x8*>(
            &sm[cur * 65536 + n * 128 + ((s ^ (n & 7)) << 4)]);
      }
#pragma unroll
      for (int m = 0; m < 2; ++m)
#pragma unroll
        for (int nf = 0; nf < 4; ++nf)
          acc[m][nf] = __builtin_amdgcn_mfma_f32_16x16x32_bf16(af[m], bfr[nf], acc[m][nf], 0, 0, 0);
    }
    __syncthreads();
  }

  // ---- transition: h2 (bias+relu, bf16) -> h2t swizzled ----
#pragma unroll
  for (int nf = 0; nf < 4; ++nf) {
    const int col = wc * 64 + nf * 16 + la;
    const float bb = b2[col];
    const int s = col >> 3, c7 = col & 7;
#pragma unroll
    for (int m = 0; m < 2; ++m) {
#pragma unroll
      for (int qq = 0; qq < 4; ++qq) {
        const int row = wr * 32 + m * 16 + q4 * 4 + qq;
        const int swz = (s & 56) | ((s ^ row) & 7);
        smU[row * 512 + swz * 8 + c7] = f2bfu(fmaxf(acc[m][nf][qq] + bb, 0.f));
      }
    }
  }
  __syncthreads();

  // ---- phase B: out64x128 = relu(h2t @ W3 + b3); W3 frags direct from L2 ----
  f32x4 acc2[2];
#pragma unroll
  for (int m = 0; m < 2; ++m) acc2[m] = (f32x4){0.f, 0.f, 0.f, 0.f};
  const int colB = wc * 16 + la;
  for (int kc = 0; kc < 16; ++kc) {
    const int s = kc * 4 + q4;
    s16x8 af2[2];
#pragma unroll
    for (int m = 0; m < 2; ++m) {
      const int row = wr * 32 + m * 16 + la;
      af2[m] = *reinterpret_cast<const s16x8*>(
          &sm[row * 1024 + (((s & 56) | ((s ^ row) & 7)) << 4)]);
    }
    const s16x8 bf2 = *reinterpret_cast<const s16x8*>(W3T + (size_t)colB * 512 + kc * 32 + q4 * 8);
#pragma unroll
    for (int m = 0; m < 2; ++m)
      acc2[m] = __builtin_amdgcn_mfma_f32_16x16x32_bf16(af2[m], bf2, acc2[m], 0, 0, 0);
  }

  // ---- epilogue: padded f32 stage -> coalesced float4 writes ----
  float* ost = (float*)(sm + 65536);  // stride 132 floats
  {
    const float bb3 = b3[colB];
#pragma unroll
    for (int m = 0; m < 2; ++m)
#pragma unroll
      for (int qq = 0; qq < 4; ++qq) {
        const int row = wr * 32 + m * 16 + q4 * 4 + qq;
        ost[row * 132 + colB] = fmaxf(acc2[m][qq] + bb3, 0.f);
      }
  }
  __syncthreads();
#pragma unroll
  for (int i = 0; i < 2; ++i) {
    const int flat = i * 1024 + tid;
    const int r = flat >> 5, gc = flat & 31;
    const float4 v = *reinterpret_cast<const float4*>(ost + r * 132 + gc * 4);
    *reinterpret_cast<float4*>(out + (size_t)(m0 + r) * 128 + gc * 4) = v;
  }
}

extern "C" void kernel_launch(void* const* d_in, const int* in_sizes, int n_in,
                              void* d_out, int out_size, void* d_ws, size_t ws_size,
                              hipStream_t stream) {
  const float* X0 = (const float*)d_in[0];
  const float* Xs = (const float*)d_in[1];
  const float* Wq = (const float*)d_in[2];
  const float* bq = (const float*)d_in[3];
  const float* Wk = (const float*)d_in[4];
  const float* bk = (const float*)d_in[5];
  const float* Wv = (const float*)d_in[6];
  const float* bv = (const float*)d_in[7];
  const float* gp = (const float*)d_in[8];
  const float* W1 = (const float*)d_in[9];
  const float* b1 = (const float*)d_in[10];
  const float* W2 = (const float*)d_in[11];
  const float* b2 = (const float*)d_in[12];
  const float* W3 = (const float*)d_in[13];
  const float* b3 = (const float*)d_in[14];

  char* ws = (char*)d_ws;
  float* Cws = (float*)(ws);                              //   4 KB
  float* Wws = (float*)(ws + 4096);                       // 256 KB
  float* Pws = (float*)(ws + 266240);                     //   1 MB
  float* Rws = (float*)(ws + 1314816);                    //   1 MB
  unsigned short* W2T = (unsigned short*)(ws + 2363392);  //   1 MB (bf16)
  unsigned short* W3T = (unsigned short*)(ws + 3411968);  // 128 KB (bf16)
  float* V0ws = (float*)(ws + 3543040);                   // 512 KB
  float* QKws = (float*)(ws + 4067328);                   // 128 KB
  float* out = (float*)d_out;

  hipLaunchKernelGGL(transpose_all_k, dim3(576), dim3(256), 0, stream, W2, W3, W2T, W3T);
  hipLaunchKernelGGL(xw_k, dim3(10, 8), dim3(256), 0, stream, X0, Wv, Wq, Wk, V0ws, QKws);
  hipLaunchKernelGGL(wsm_k, dim3(256), dim3(256), 0, stream, Xs, QKws, bq, Wws);
  hipLaunchKernelGGL(prc_k, dim3(16, 17), dim3(256), 0, stream, V0ws, X0, bv, W1, gp, b1, Pws, Rws, Cws);
  hipLaunchKernelGGL(fused_k, dim3(1024), dim3(1024), 0, stream,
                     Xs, gp, W2T, b2, W3T, b3, Cws, Wws, Pws, Rws, out);
}

// Round 7
// 213.740 us; speedup vs baseline: 1.3363x; 1.0057x over previous
//
#include <hip/hip_runtime.h>
#include <hip/hip_bf16.h>

typedef __attribute__((ext_vector_type(8))) short s16x8;
typedef __attribute__((ext_vector_type(16))) float f32x16;

__device__ __forceinline__ unsigned short f2bfu(float x) {
  __hip_bfloat16 b = __float2bfloat16(x);
  return *reinterpret_cast<unsigned short*>(&b);
}
__device__ __forceinline__ short f2bfs(float x) { return (short)f2bfu(x); }

// -------- merged transpose + downcast: W2T[512][1024], W3T[128][512] --------
__global__ __launch_bounds__(256) void transpose_all_k(
    const float* __restrict__ W2, const float* __restrict__ W3,
    unsigned short* __restrict__ W2T, unsigned short* __restrict__ W3T) {
  __shared__ float t[32][33];
  int blk = blockIdx.x;
  const float* src;
  unsigned short* dst;
  int R, C, bx, by;
  if (blk < 512) { src = W2; dst = W2T; R = 1024; C = 512; bx = blk & 15; by = blk >> 4; }
  else { blk -= 512; src = W3; dst = W3T; R = 512; C = 128; bx = blk & 3; by = blk >> 2; }
  const int c0 = bx * 32, r0 = by * 32;
  const int tx = threadIdx.x & 31, ty = threadIdx.x >> 5;
#pragma unroll
  for (int i = 0; i < 32; i += 8)
    t[ty + i][tx] = src[(size_t)(r0 + ty + i) * C + (c0 + tx)];
  __syncthreads();
#pragma unroll
  for (int i = 0; i < 32; i += 8)
    dst[(size_t)(c0 + ty + i) * R + (r0 + tx)] = f2bfu(t[tx][ty + i]);
}

// -------- xw_k: [V0 | QK] = X0 @ [Wv | Wq | Wk], 32x64 tiles, grid (10,8) ----
__global__ __launch_bounds__(256) void xw_k(const float* __restrict__ X0,
                                            const float* __restrict__ Wv,
                                            const float* __restrict__ Wq,
                                            const float* __restrict__ Wk,
                                            float* __restrict__ V0ws,
                                            float* __restrict__ QKws) {
  __shared__ float As[32][17];
  __shared__ float Bs[16][68];
  const int tid = threadIdx.x;
  const int bn = blockIdx.x, bm = blockIdx.y;
  const int tx = tid & 15, ty = tid >> 4;
  float acc[2][4] = {};
  for (int k0 = 0; k0 < 512; k0 += 16) {
    if (tid < 128) {
      const int row = tid >> 2, kk = (tid & 3) * 4;
      const float4 v = *reinterpret_cast<const float4*>(X0 + (size_t)(bm * 32 + row) * 512 + k0 + kk);
      As[row][kk] = v.x; As[row][kk + 1] = v.y; As[row][kk + 2] = v.z; As[row][kk + 3] = v.w;
    }
    {
      const int k = tid >> 4, n4 = (tid & 15) * 4;
      float4 v;
      if (bn < 8)       v = *reinterpret_cast<const float4*>(Wv + (size_t)(k0 + k) * 512 + bn * 64 + n4);
      else if (bn == 8) v = *reinterpret_cast<const float4*>(Wq + (size_t)(k0 + k) * 64 + n4);
      else              v = *reinterpret_cast<const float4*>(Wk + (size_t)(k0 + k) * 64 + n4);
      Bs[k][n4] = v.x; Bs[k][n4 + 1] = v.y; Bs[k][n4 + 2] = v.z; Bs[k][n4 + 3] = v.w;
    }
    __syncthreads();
#pragma unroll
    for (int kk = 0; kk < 16; ++kk) {
      float a[2], bb[4];
#pragma unroll
      for (int i = 0; i < 2; ++i) a[i] = As[ty * 2 + i][kk];
#pragma unroll
      for (int j = 0; j < 4; ++j) bb[j] = Bs[kk][tx * 4 + j];
#pragma unroll
      for (int i = 0; i < 2; ++i)
#pragma unroll
        for (int j = 0; j < 4; ++j) acc[i][j] = fmaf(a[i], bb[j], acc[i][j]);
    }
    __syncthreads();
  }
#pragma unroll
  for (int i = 0; i < 2; ++i) {
    const int row = bm * 32 + ty * 2 + i;
#pragma unroll
    for (int j = 0; j < 4; ++j) {
      const int n = tx * 4 + j;
      if (bn < 8)       V0ws[(size_t)row * 512 + bn * 64 + n] = acc[i][j];
      else if (bn == 8) QKws[(size_t)row * 128 + n] = acc[i][j];
      else              QKws[(size_t)row * 128 + 64 + n] = acc[i][j];
    }
  }
}

// -------- wsm_k: per-batch softmax weights w[256] --------
__global__ __launch_bounds__(256) void wsm_k(const float* __restrict__ Xs,
                                             const float* __restrict__ QKws,
                                             const float* __restrict__ bq,
                                             float* __restrict__ Wws) {
  const int b = blockIdx.x, t = threadIdx.x;
  __shared__ float sv[256];
  __shared__ float scal[4];
  sv[t] = (t == 0) ? 1.0f : Xs[b * 255 + t - 1];
  __syncthreads();
  if (t == 0) {
    float al = 0, g2 = 0;
    for (int j = 0; j < 64; ++j) {
      al = fmaf(QKws[b * 128 + j], QKws[b * 128 + 64 + j], al);
      g2 = fmaf(bq[j], QKws[b * 128 + 64 + j], g2);
    }
    float mx = sv[0], mn = sv[0];
    for (int m2 = 1; m2 < 256; ++m2) { mx = fmaxf(mx, sv[m2]); mn = fminf(mn, sv[m2]); }
    scal[0] = al; scal[1] = g2; scal[2] = mx; scal[3] = mn;
  }
  __syncthreads();
  const float c = fmaf(scal[0], sv[t], scal[1]);
  const float M = (c >= 0.f) ? c * scal[2] : c * scal[3];
  float Z = 0, Wm = 0;
  for (int m2 = 0; m2 < 256; ++m2) {
    const float e = __expf(fmaf(c, sv[m2], -M));
    Z += e;
    Wm = fmaf(sv[m2], e, Wm);
  }
  Wws[b * 256 + t] = Wm / Z;
}

// -------- prc_k: [P; R; Cpre] = [V0; X0; bv] @ W1, 32x64 tiles, grid (16,17) -
__global__ __launch_bounds__(256) void prc_k(const float* __restrict__ V0ws,
                                             const float* __restrict__ X0,
                                             const float* __restrict__ bv,
                                             const float* __restrict__ W1,
                                             const float* __restrict__ gp,
                                             const float* __restrict__ b1,
                                             float* __restrict__ Pws,
                                             float* __restrict__ Rws,
                                             float* __restrict__ Cws) {
  __shared__ float As[32][17];
  __shared__ float Bs[16][68];
  const int tid = threadIdx.x;
  const int bnx = blockIdx.x, bmy = blockIdx.y;
  const int tx = tid & 15, ty = tid >> 4;
  float acc[2][4] = {};
  for (int k0 = 0; k0 < 512; k0 += 16) {
    if (tid < 128) {
      const int row = tid >> 2, kk = (tid & 3) * 4;
      const int rowg = bmy * 32 + row;
      float4 v = {0.f, 0.f, 0.f, 0.f};
      if (rowg < 256)       v = *reinterpret_cast<const float4*>(V0ws + (size_t)rowg * 512 + k0 + kk);
      else if (rowg < 512)  v = *reinterpret_cast<const float4*>(X0 + (size_t)(rowg - 256) * 512 + k0 + kk);
      else if (rowg == 512) v = *reinterpret_cast<const float4*>(bv + k0 + kk);
      As[row][kk] = v.x; As[row][kk + 1] = v.y; As[row][kk + 2] = v.z; As[row][kk + 3] = v.w;
    }
    {
      const int k = tid >> 4, n4 = (tid & 15) * 4;
      const float4 v = *reinterpret_cast<const float4*>(W1 + (size_t)(k0 + k) * 1024 + bnx * 64 + n4);
      Bs[k][n4] = v.x; Bs[k][n4 + 1] = v.y; Bs[k][n4 + 2] = v.z; Bs[k][n4 + 3] = v.w;
    }
    __syncthreads();
#pragma unroll
    for (int kk = 0; kk < 16; ++kk) {
      float a[2], bb[4];
#pragma unroll
      for (int i = 0; i < 2; ++i) a[i] = As[ty * 2 + i][kk];
#pragma unroll
      for (int j = 0; j < 4; ++j) bb[j] = Bs[kk][tx * 4 + j];
#pragma unroll
      for (int i = 0; i < 2; ++i)
#pragma unroll
        for (int j = 0; j < 4; ++j) acc[i][j] = fmaf(a[i], bb[j], acc[i][j]);
    }
    __syncthreads();
  }
  const float g = gp[0];
#pragma unroll
  for (int i = 0; i < 2; ++i) {
    const int rowg = bmy * 32 + ty * 2 + i;
#pragma unroll
    for (int j = 0; j < 4; ++j) {
      const int col = bnx * 64 + tx * 4 + j;
      if (rowg < 256)       Pws[(size_t)rowg * 1024 + col] = acc[i][j];
      else if (rowg < 512)  Rws[(size_t)(rowg - 256) * 1024 + col] = acc[i][j];
      else if (rowg == 512) Cws[col] = fmaf(g, acc[i][j], b1[col]);
    }
  }
}

// -------- fused: out = relu(relu(h1@W2+b2)@W3 + b3), 32x32 MFMA --------
// BM=128, BN=512, BK=64, 1024 thr (16 waves), grid 512 (2 rounds).
// Phase A: waves 2(M)x8(N), wave tile 64x64 (2x2 frags of 32x32x16).
//   A generated in registers (rank-2 form); B from LDS dbuf.
// LDS: Bt dbuf 2x64KB [0,131072): row n at n*128B, slot p holds k-slot p^(n&7)
//      PRC f32 12KB [131072,143360)
// Phase B: h2t 128KB reuses [0,131072): row r at r*1024B, slot swz (s&56)|((s^r)&7)
//   waves 4(M)x4(N), one 32x32 frag each, K=512; W3T direct from L1/L2.
__global__ __launch_bounds__(1024, 4) void fused_k(
    const float* __restrict__ Xs, const float* __restrict__ gp,
    const unsigned short* __restrict__ W2T,  // [512][1024] bf16
    const float* __restrict__ b2,
    const unsigned short* __restrict__ W3T,  // [128][512] bf16
    const float* __restrict__ b3,
    const float* __restrict__ Cws, const float* __restrict__ Wws,
    const float* __restrict__ Pws, const float* __restrict__ Rws,
    float* __restrict__ out)  // [65536][128] f32
{
  __shared__ __align__(16) unsigned char sm[143360];
  unsigned short* smU = (unsigned short*)sm;
  float* Pl = (float*)(sm + 131072);
  const int tid = threadIdx.x;
  const int lane = tid & 63, wid = tid >> 6;
  const int la31 = lane & 31, hi = lane >> 5;
  const int wr = wid >> 3, wc = wid & 7;  // phase A: 2 x 8
  const int m0 = blockIdx.x * 128;
  const int b = blockIdx.x >> 1;
  const float g = gp[0];

  // per-lane row scalars for the 2 m-frags (rows wr*64 + m*32 + la31)
  float gwm[2], srm[2];
#pragma unroll
  for (int m = 0; m < 2; ++m) {
    const int tok = (m0 & 255) + wr * 64 + m * 32 + la31;
    gwm[m] = g * Wws[b * 256 + tok];
    srm[m] = (tok == 0) ? 1.0f : Xs[b * 255 + tok - 1];
  }

  // stage PRC into LDS (P@0, R@1024, C@2048 floats)
  Pl[tid] = Pws[b * 1024 + tid];
  Pl[1024 + tid] = Rws[b * 1024 + tid];
  if (tid < 1024) Pl[2048 + tid] = Cws[tid];

  // B staging: 4 DMA/wave, each fills 8 rows x 128B line, XOR-swizzled source
  auto stageB = [&](int buf, int k0) {
#pragma unroll
    for (int ii = 0; ii < 4; ++ii) {
      const int r0 = (wid * 4 + ii) * 8;
      const int row = r0 + (lane >> 3);
      const int sl = (lane & 7) ^ (row & 7);
      const unsigned short* src = W2T + (size_t)row * 1024 + k0 + sl * 8;
      __builtin_amdgcn_global_load_lds(
          (const __attribute__((address_space(1))) void*)src,
          (__attribute__((address_space(3))) void*)&sm[buf * 65536 + r0 * 128],
          16, 0, 0);
    }
  };

  f32x16 acc[2][2];
#pragma unroll
  for (int m = 0; m < 2; ++m)
#pragma unroll
    for (int n = 0; n < 2; ++n)
#pragma unroll
      for (int i = 0; i < 16; ++i) acc[m][n][i] = 0.f;

  stageB(0, 0);
  __syncthreads();

  // ---- phase A: 16 K-steps of 64 ----
  for (int step = 0; step < 16; ++step) {
    const int cur = step & 1;
    if (step < 15) stageB(cur ^ 1, (step + 1) * 64);
#pragma unroll
    for (int ksub = 0; ksub < 4; ++ksub) {
      const int kb = step * 64 + ksub * 16 + hi * 8;
      const float4 P0 = *(const float4*)(Pl + kb);
      const float4 P1 = *(const float4*)(Pl + kb + 4);
      const float4 R0 = *(const float4*)(Pl + 1024 + kb);
      const float4 R1 = *(const float4*)(Pl + 1024 + kb + 4);
      const float4 C0 = *(const float4*)(Pl + 2048 + kb);
      const float4 C1 = *(const float4*)(Pl + 2048 + kb + 4);
      s16x8 af[2];
#pragma unroll
      for (int m = 0; m < 2; ++m) {
        const float gw = gwm[m], sr = srm[m];
        s16x8 v;
        v[0] = f2bfs(fmaxf(fmaf(gw, P0.x, fmaf(sr, R0.x, C0.x)), 0.f));
        v[1] = f2bfs(fmaxf(fmaf(gw, P0.y, fmaf(sr, R0.y, C0.y)), 0.f));
        v[2] = f2bfs(fmaxf(fmaf(gw, P0.z, fmaf(sr, R0.z, C0.z)), 0.f));
        v[3] = f2bfs(fmaxf(fmaf(gw, P0.w, fmaf(sr, R0.w, C0.w)), 0.f));
        v[4] = f2bfs(fmaxf(fmaf(gw, P1.x, fmaf(sr, R1.x, C1.x)), 0.f));
        v[5] = f2bfs(fmaxf(fmaf(gw, P1.y, fmaf(sr, R1.y, C1.y)), 0.f));
        v[6] = f2bfs(fmaxf(fmaf(gw, P1.z, fmaf(sr, R1.z, C1.z)), 0.f));
        v[7] = f2bfs(fmaxf(fmaf(gw, P1.w, fmaf(sr, R1.w, C1.w)), 0.f));
        af[m] = v;
      }
      const int sg = ksub * 2 + hi;  // k-slot 0..7
      s16x8 bfr[2];
#pragma unroll
      for (int n = 0; n < 2; ++n) {
        const int nn = wc * 64 + n * 32 + la31;
        bfr[n] = *(const s16x8*)(&sm[cur * 65536 + nn * 128 + ((sg ^ (nn & 7)) << 4)]);
      }
#pragma unroll
      for (int m = 0; m < 2; ++m)
#pragma unroll
        for (int n = 0; n < 2; ++n)
          acc[m][n] = __builtin_amdgcn_mfma_f32_32x32x16_bf16(af[m], bfr[n], acc[m][n], 0, 0, 0);
    }
    __syncthreads();
  }

  // ---- transition: h2 (bias+relu, bf16) -> h2t swizzled in [0,128K) ----
#pragma unroll
  for (int n = 0; n < 2; ++n) {
    const int col = wc * 64 + n * 32 + la31;
    const float bb = b2[col];
    const int sc = col >> 3, c7 = col & 7;
#pragma unroll
    for (int m = 0; m < 2; ++m) {
#pragma unroll
      for (int reg = 0; reg < 16; ++reg) {
        const int row = wr * 64 + m * 32 + (reg & 3) + 8 * (reg >> 2) + 4 * hi;
        const int sp = (sc & 56) | ((sc ^ row) & 7);
        smU[row * 512 + sp * 8 + c7] = f2bfu(fmaxf(acc[m][n][reg] + bb, 0.f));
      }
    }
  }
  __syncthreads();

  // ---- phase B: out 128x128 = relu(h2t @ W3 + b3), waves 4x4, K=512 ----
  const int wm = wid >> 2, wn = wid & 3;
  const int rowB = wm * 32 + la31;
  const int colB = wn * 32 + la31;
  const float b3v = b3[colB];
  f32x16 acc2;
#pragma unroll
  for (int i = 0; i < 16; ++i) acc2[i] = 0.f;
#pragma unroll 4
  for (int s = 0; s < 32; ++s) {
    const int sg = s * 2 + hi;  // slot 0..63
    const s16x8 af2 = *(const s16x8*)(
        &sm[rowB * 1024 + (((sg & 56) | ((sg ^ rowB) & 7)) << 4)]);
    const s16x8 bf2 = *(const s16x8*)(W3T + (size_t)colB * 512 + s * 16 + hi * 8);
    acc2 = __builtin_amdgcn_mfma_f32_32x32x16_bf16(af2, bf2, acc2, 0, 0, 0);
  }
  // direct coalesced f32 stores (two 128B lines per reg-store across the wave)
#pragma unroll
  for (int reg = 0; reg < 16; ++reg) {
    const int rowg = m0 + wm * 32 + (reg & 3) + 8 * (reg >> 2) + 4 * hi;
    out[(size_t)rowg * 128 + colB] = fmaxf(acc2[reg] + b3v, 0.f);
  }
}

extern "C" void kernel_launch(void* const* d_in, const int* in_sizes, int n_in,
                              void* d_out, int out_size, void* d_ws, size_t ws_size,
                              hipStream_t stream) {
  const float* X0 = (const float*)d_in[0];
  const float* Xs = (const float*)d_in[1];
  const float* Wq = (const float*)d_in[2];
  const float* bq = (const float*)d_in[3];
  const float* Wk = (const float*)d_in[4];
  const float* bk = (const float*)d_in[5];
  const float* Wv = (const float*)d_in[6];
  const float* bv = (const float*)d_in[7];
  const float* gp = (const float*)d_in[8];
  const float* W1 = (const float*)d_in[9];
  const float* b1 = (const float*)d_in[10];
  const float* W2 = (const float*)d_in[11];
  const float* b2 = (const float*)d_in[12];
  const float* W3 = (const float*)d_in[13];
  const float* b3 = (const float*)d_in[14];

  char* ws = (char*)d_ws;
  float* Cws = (float*)(ws);                              //   4 KB
  float* Wws = (float*)(ws + 4096);                       // 256 KB
  float* Pws = (float*)(ws + 266240);                     //   1 MB
  float* Rws = (float*)(ws + 1314816);                    //   1 MB
  unsigned short* W2T = (unsigned short*)(ws + 2363392);  //   1 MB (bf16)
  unsigned short* W3T = (unsigned short*)(ws + 3411968);  // 128 KB (bf16)
  float* V0ws = (float*)(ws + 3543040);                   // 512 KB
  float* QKws = (float*)(ws + 4067328);                   // 128 KB
  float* out = (float*)d_out;

  hipLaunchKernelGGL(transpose_all_k, dim3(576), dim3(256), 0, stream, W2, W3, W2T, W3T);
  hipLaunchKernelGGL(xw_k, dim3(10, 8), dim3(256), 0, stream, X0, Wv, Wq, Wk, V0ws, QKws);
  hipLaunchKernelGGL(wsm_k, dim3(256), dim3(256), 0, stream, Xs, QKws, bq, Wws);
  hipLaunchKernelGGL(prc_k, dim3(16, 17), dim3(256), 0, stream, V0ws, X0, bv, W1, gp, b1, Pws, Rws, Cws);
  hipLaunchKernelGGL(fused_k, dim3(512), dim3(1024), 0, stream,
                     Xs, gp, W2T, b2, W3T, b3, Cws, Wws, Pws, Rws, out);
}

// Round 8
// 180.509 us; speedup vs baseline: 1.5823x; 1.1841x over previous
//
#include <hip/hip_runtime.h>
#include <hip/hip_bf16.h>

typedef __attribute__((ext_vector_type(8))) short s16x8;
typedef __attribute__((ext_vector_type(16))) float f32x16;

__device__ __forceinline__ unsigned short f2bfu(float x) {
  __hip_bfloat16 b = __float2bfloat16(x);
  return *reinterpret_cast<unsigned short*>(&b);
}
__device__ __forceinline__ short f2bfs(float x) { return (short)f2bfu(x); }

// ======== prep1: transpose/downcast W2,W3 + xw ([V0|QK] = X0@[Wv|Wq|Wk]) =====
// blocks 0..575: transpose; 576..655: xw (80 blocks)
__global__ __launch_bounds__(256) void prep1_k(
    const float* __restrict__ W2, const float* __restrict__ W3,
    unsigned short* __restrict__ W2T, unsigned short* __restrict__ W3T,
    const float* __restrict__ X0, const float* __restrict__ Wv,
    const float* __restrict__ Wq, const float* __restrict__ Wk,
    float* __restrict__ V0ws, float* __restrict__ QKws) {
  const int tid = threadIdx.x;
  if (blockIdx.x < 576) {
    __shared__ float t[32][33];
    int blk = blockIdx.x;
    const float* src;
    unsigned short* dst;
    int R, C, bx, by;
    if (blk < 512) { src = W2; dst = W2T; R = 1024; C = 512; bx = blk & 15; by = blk >> 4; }
    else { blk -= 512; src = W3; dst = W3T; R = 512; C = 128; bx = blk & 3; by = blk >> 2; }
    const int c0 = bx * 32, r0 = by * 32;
    const int tx = tid & 31, ty = tid >> 5;
#pragma unroll
    for (int i = 0; i < 32; i += 8)
      t[ty + i][tx] = src[(size_t)(r0 + ty + i) * C + (c0 + tx)];
    __syncthreads();
#pragma unroll
    for (int i = 0; i < 32; i += 8)
      dst[(size_t)(c0 + ty + i) * R + (r0 + tx)] = f2bfu(t[tx][ty + i]);
    return;
  }
  // xw part
  __shared__ float As[32][17];
  __shared__ float Bs[16][68];
  const int r = blockIdx.x - 576;
  const int bn = r % 10, bm = r / 10;
  const int tx = tid & 15, ty = tid >> 4;
  float acc[2][4] = {};
  for (int k0 = 0; k0 < 512; k0 += 16) {
    if (tid < 128) {
      const int row = tid >> 2, kk = (tid & 3) * 4;
      const float4 v = *reinterpret_cast<const float4*>(X0 + (size_t)(bm * 32 + row) * 512 + k0 + kk);
      As[row][kk] = v.x; As[row][kk + 1] = v.y; As[row][kk + 2] = v.z; As[row][kk + 3] = v.w;
    }
    {
      const int k = tid >> 4, n4 = (tid & 15) * 4;
      float4 v;
      if (bn < 8)       v = *reinterpret_cast<const float4*>(Wv + (size_t)(k0 + k) * 512 + bn * 64 + n4);
      else if (bn == 8) v = *reinterpret_cast<const float4*>(Wq + (size_t)(k0 + k) * 64 + n4);
      else              v = *reinterpret_cast<const float4*>(Wk + (size_t)(k0 + k) * 64 + n4);
      Bs[k][n4] = v.x; Bs[k][n4 + 1] = v.y; Bs[k][n4 + 2] = v.z; Bs[k][n4 + 3] = v.w;
    }
    __syncthreads();
#pragma unroll
    for (int kk = 0; kk < 16; ++kk) {
      float a[2], bb[4];
#pragma unroll
      for (int i = 0; i < 2; ++i) a[i] = As[ty * 2 + i][kk];
#pragma unroll
      for (int j = 0; j < 4; ++j) bb[j] = Bs[kk][tx * 4 + j];
#pragma unroll
      for (int i = 0; i < 2; ++i)
#pragma unroll
        for (int j = 0; j < 4; ++j) acc[i][j] = fmaf(a[i], bb[j], acc[i][j]);
    }
    __syncthreads();
  }
#pragma unroll
  for (int i = 0; i < 2; ++i) {
    const int row = bm * 32 + ty * 2 + i;
#pragma unroll
    for (int j = 0; j < 4; ++j) {
      const int n = tx * 4 + j;
      if (bn < 8)       V0ws[(size_t)row * 512 + bn * 64 + n] = acc[i][j];
      else if (bn == 8) QKws[(size_t)row * 128 + n] = acc[i][j];
      else              QKws[(size_t)row * 128 + 64 + n] = acc[i][j];
    }
  }
}

// ======== prep2: wsm (softmax weights) + prc ([P;R;C] GEMM) =====
// blocks 0..255: wsm; 256..527: prc (272 blocks)
__global__ __launch_bounds__(256) void prep2_k(
    const float* __restrict__ Xs, const float* __restrict__ QKws,
    const float* __restrict__ bq, float* __restrict__ Wws,
    const float* __restrict__ V0ws, const float* __restrict__ X0,
    const float* __restrict__ bv, const float* __restrict__ W1,
    const float* __restrict__ gp, const float* __restrict__ b1,
    float* __restrict__ Pws, float* __restrict__ Rws, float* __restrict__ Cws) {
  const int tid = threadIdx.x;
  if (blockIdx.x < 256) {
    const int b = blockIdx.x, t = tid;
    __shared__ float sv[256];
    __shared__ float scal[4];
    sv[t] = (t == 0) ? 1.0f : Xs[b * 255 + t - 1];
    __syncthreads();
    if (t == 0) {
      float al = 0, g2 = 0;
      for (int j = 0; j < 64; ++j) {
        al = fmaf(QKws[b * 128 + j], QKws[b * 128 + 64 + j], al);
        g2 = fmaf(bq[j], QKws[b * 128 + 64 + j], g2);
      }
      float mx = sv[0], mn = sv[0];
      for (int m2 = 1; m2 < 256; ++m2) { mx = fmaxf(mx, sv[m2]); mn = fminf(mn, sv[m2]); }
      scal[0] = al; scal[1] = g2; scal[2] = mx; scal[3] = mn;
    }
    __syncthreads();
    const float c = fmaf(scal[0], sv[t], scal[1]);
    const float M = (c >= 0.f) ? c * scal[2] : c * scal[3];
    float Z = 0, Wm = 0;
    for (int m2 = 0; m2 < 256; ++m2) {
      const float e = __expf(fmaf(c, sv[m2], -M));
      Z += e;
      Wm = fmaf(sv[m2], e, Wm);
    }
    Wws[b * 256 + t] = Wm / Z;
    return;
  }
  // prc part
  __shared__ float As[32][17];
  __shared__ float Bs[16][68];
  const int r = blockIdx.x - 256;
  const int bnx = r % 16, bmy = r / 16;
  const int tx = tid & 15, ty = tid >> 4;
  float acc[2][4] = {};
  for (int k0 = 0; k0 < 512; k0 += 16) {
    if (tid < 128) {
      const int row = tid >> 2, kk = (tid & 3) * 4;
      const int rowg = bmy * 32 + row;
      float4 v = {0.f, 0.f, 0.f, 0.f};
      if (rowg < 256)       v = *reinterpret_cast<const float4*>(V0ws + (size_t)rowg * 512 + k0 + kk);
      else if (rowg < 512)  v = *reinterpret_cast<const float4*>(X0 + (size_t)(rowg - 256) * 512 + k0 + kk);
      else if (rowg == 512) v = *reinterpret_cast<const float4*>(bv + k0 + kk);
      As[row][kk] = v.x; As[row][kk + 1] = v.y; As[row][kk + 2] = v.z; As[row][kk + 3] = v.w;
    }
    {
      const int k = tid >> 4, n4 = (tid & 15) * 4;
      const float4 v = *reinterpret_cast<const float4*>(W1 + (size_t)(k0 + k) * 1024 + bnx * 64 + n4);
      Bs[k][n4] = v.x; Bs[k][n4 + 1] = v.y; Bs[k][n4 + 2] = v.z; Bs[k][n4 + 3] = v.w;
    }
    __syncthreads();
#pragma unroll
    for (int kk = 0; kk < 16; ++kk) {
      float a[2], bb[4];
#pragma unroll
      for (int i = 0; i < 2; ++i) a[i] = As[ty * 2 + i][kk];
#pragma unroll
      for (int j = 0; j < 4; ++j) bb[j] = Bs[kk][tx * 4 + j];
#pragma unroll
      for (int i = 0; i < 2; ++i)
#pragma unroll
        for (int j = 0; j < 4; ++j) acc[i][j] = fmaf(a[i], bb[j], acc[i][j]);
    }
    __syncthreads();
  }
  const float g = gp[0];
#pragma unroll
  for (int i = 0; i < 2; ++i) {
    const int rowg = bmy * 32 + ty * 2 + i;
#pragma unroll
    for (int j = 0; j < 4; ++j) {
      const int col = bnx * 64 + tx * 4 + j;
      if (rowg < 256)       Pws[(size_t)rowg * 1024 + col] = acc[i][j];
      else if (rowg < 512)  Rws[(size_t)(rowg - 256) * 1024 + col] = acc[i][j];
      else if (rowg == 512) Cws[col] = fmaf(g, acc[i][j], b1[col]);
    }
  }
}

// ======== fused: out = relu(relu(h1@W2+b2)@W3 + b3) =====
// 512 thr (8 waves), grid 512 (m0 = bid*128). Phase A: waves 2m x 4n, wave
// tile 64x128 (2x4 frags of 32x32x16), BK=64, 16 steps; A generated in
// registers from rank-2 form (dup 4x); B (W2T) in LDS dbuf 2x64KB, row n at
// n*128B with slot p holding k-oct p^(n&7).
// LDS: Bt dbuf [0,131072); PRC f32 12KB [131072,143360).
// Phase B: h2t 128KB [0,131072) (row r at r*1024B, slot swz (s&56)|((s^r)&7));
//          W3c 16KB chunks [131072,147456); direct coalesced f32 stores.
__global__ __launch_bounds__(512, 2) void fused_k(
    const float* __restrict__ Xs, const float* __restrict__ gp,
    const unsigned short* __restrict__ W2T,  // [512][1024] bf16
    const float* __restrict__ b2,
    const unsigned short* __restrict__ W3T,  // [128][512] bf16
    const float* __restrict__ b3,
    const float* __restrict__ Cws, const float* __restrict__ Wws,
    const float* __restrict__ Pws, const float* __restrict__ Rws,
    float* __restrict__ out)  // [65536][128] f32
{
  __shared__ __align__(16) unsigned char sm[147456];
  unsigned short* smU = (unsigned short*)sm;
  float* PRC = (float*)(sm + 131072);  // P[1024] | R[1024] | C[1024]
  const int tid = threadIdx.x;
  const int lane = tid & 63, wid = tid >> 6;  // 8 waves
  const int la31 = lane & 31, hi = lane >> 5;
  const int wr = wid >> 2, wc = wid & 3;  // 2m x 4n
  const int m0 = blockIdx.x * 128;
  const int b = m0 >> 8;
  const float g = gp[0];

  // per-lane row scalars for the 2 m-frags
  float gwm[2], srm[2];
#pragma unroll
  for (int m = 0; m < 2; ++m) {
    const int tok = (m0 & 255) + wr * 64 + m * 32 + la31;
    gwm[m] = g * Wws[b * 256 + tok];
    srm[m] = (tok == 0) ? 1.0f : Xs[b * 255 + tok - 1];
  }

  // PRC -> LDS (f32): 3072 / 512 = 6 each
#pragma unroll
  for (int i = 0; i < 6; ++i) {
    const int idx = i * 512 + tid;
    float v;
    if (idx < 1024)      v = Pws[b * 1024 + idx];
    else if (idx < 2048) v = Rws[b * 1024 + (idx - 1024)];
    else                 v = Cws[idx - 2048];
    PRC[idx] = v;
  }

  // B staging: 8 DMA/wave, each = 8 rows x one full 128B line, swizzled src
  auto stageB = [&](int buf, int k0) {
#pragma unroll
    for (int ii = 0; ii < 8; ++ii) {
      const int r0 = (wid * 8 + ii) * 8;
      const int row = r0 + (lane >> 3);
      const int sl = (lane & 7) ^ (row & 7);
      const unsigned short* src = W2T + (size_t)row * 1024 + k0 + sl * 8;
      __builtin_amdgcn_global_load_lds(
          (const __attribute__((address_space(1))) void*)src,
          (__attribute__((address_space(3))) void*)&sm[buf * 65536 + r0 * 128],
          16, 0, 0);
    }
  };

  f32x16 acc[2][4];
#pragma unroll
  for (int m = 0; m < 2; ++m)
#pragma unroll
    for (int n = 0; n < 4; ++n)
#pragma unroll
      for (int i = 0; i < 16; ++i) acc[m][n][i] = 0.f;

  stageB(0, 0);
  __syncthreads();

  // ---- phase A: 16 K-steps of 64 ----
  for (int step = 0; step < 16; ++step) {
    const int cur = step & 1;
    if (step < 15) stageB(cur ^ 1, (step + 1) * 64);
    // generate A fragments (af[m][ks]) in registers from rank-2 form
    s16x8 af[2][4];
#pragma unroll
    for (int ks = 0; ks < 4; ++ks) {
      const int kb = step * 64 + ks * 16 + hi * 8;
      const float4 P0 = *(const float4*)(PRC + kb);
      const float4 P1 = *(const float4*)(PRC + kb + 4);
      const float4 R0 = *(const float4*)(PRC + 1024 + kb);
      const float4 R1 = *(const float4*)(PRC + 1024 + kb + 4);
      const float4 C0 = *(const float4*)(PRC + 2048 + kb);
      const float4 C1 = *(const float4*)(PRC + 2048 + kb + 4);
#pragma unroll
      for (int m = 0; m < 2; ++m) {
        const float gw = gwm[m], sr = srm[m];
        s16x8 v;
        v[0] = f2bfs(fmaxf(fmaf(gw, P0.x, fmaf(sr, R0.x, C0.x)), 0.f));
        v[1] = f2bfs(fmaxf(fmaf(gw, P0.y, fmaf(sr, R0.y, C0.y)), 0.f));
        v[2] = f2bfs(fmaxf(fmaf(gw, P0.z, fmaf(sr, R0.z, C0.z)), 0.f));
        v[3] = f2bfs(fmaxf(fmaf(gw, P0.w, fmaf(sr, R0.w, C0.w)), 0.f));
        v[4] = f2bfs(fmaxf(fmaf(gw, P1.x, fmaf(sr, R1.x, C1.x)), 0.f));
        v[5] = f2bfs(fmaxf(fmaf(gw, P1.y, fmaf(sr, R1.y, C1.y)), 0.f));
        v[6] = f2bfs(fmaxf(fmaf(gw, P1.z, fmaf(sr, R1.z, C1.z)), 0.f));
        v[7] = f2bfs(fmaxf(fmaf(gw, P1.w, fmaf(sr, R1.w, C1.w)), 0.f));
        af[m][ks] = v;
      }
    }
#pragma unroll
    for (int ks = 0; ks < 4; ++ks) {
      const int sg = ks * 2 + hi;  // k-oct 0..7
#pragma unroll
      for (int nf = 0; nf < 4; ++nf) {
        const int n = wc * 128 + nf * 32 + la31;
        const s16x8 bfr = *(const s16x8*)(&sm[cur * 65536 + n * 128 + ((sg ^ (n & 7)) << 4)]);
#pragma unroll
        for (int m = 0; m < 2; ++m)
          acc[m][nf] = __builtin_amdgcn_mfma_f32_32x32x16_bf16(af[m][ks], bfr, acc[m][nf], 0, 0, 0);
      }
    }
    __syncthreads();
  }

  // ---- transition: h2 (bias+relu, bf16) -> h2t swizzled [0,128K) ----
#pragma unroll
  for (int nf = 0; nf < 4; ++nf) {
    const int col = wc * 128 + nf * 32 + la31;
    const float bb = b2[col];
    const int sc = col >> 3, c7 = col & 7;
#pragma unroll
    for (int m = 0; m < 2; ++m) {
#pragma unroll
      for (int reg = 0; reg < 16; ++reg) {
        const int row = wr * 64 + m * 32 + (reg & 3) + 8 * (reg >> 2) + 4 * hi;
        const int sp = (sc & 56) | ((sc ^ row) & 7);
        smU[row * 512 + sp * 8 + c7] = f2bfu(fmaxf(acc[m][nf][reg] + bb, 0.f));
      }
    }
  }

  // ---- phase B: out 128x128 = relu(h2t @ W3 + b3); W3 in 16KB LDS chunks ----
  f32x16 acc2[2];
#pragma unroll
  for (int m = 0; m < 2; ++m)
#pragma unroll
    for (int i = 0; i < 16; ++i) acc2[m][i] = 0.f;

  for (int kc = 0; kc < 8; ++kc) {
    // stage W3 chunk: rows c 0..127 x 64 k, 2 DMA/wave
#pragma unroll
    for (int ii = 0; ii < 2; ++ii) {
      const int r0 = (wid * 2 + ii) * 8;
      const int c = r0 + (lane >> 3);
      const int sl = (lane & 7) ^ (c & 7);
      const unsigned short* src = W3T + (size_t)c * 512 + kc * 64 + sl * 8;
      __builtin_amdgcn_global_load_lds(
          (const __attribute__((address_space(1))) void*)src,
          (__attribute__((address_space(3))) void*)&sm[131072 + r0 * 128],
          16, 0, 0);
    }
    __syncthreads();  // W3c ready; also covers transition (kc=0) / prev reads
#pragma unroll
    for (int ks = 0; ks < 4; ++ks) {
      const int sgk = ks * 2 + hi;           // oct within chunk (0..7)
      const int soct = kc * 8 + sgk;         // h2t oct (0..63)
      const int c = wc * 32 + la31;
      const s16x8 bfw = *(const s16x8*)(&sm[131072 + c * 128 + ((sgk ^ (c & 7)) << 4)]);
#pragma unroll
      for (int m = 0; m < 2; ++m) {
        const int row = wr * 64 + m * 32 + la31;
        const int sp = (soct & 56) | ((soct ^ row) & 7);
        const s16x8 afh = *(const s16x8*)(&sm[row * 1024 + (sp << 4)]);
        acc2[m] = __builtin_amdgcn_mfma_f32_32x32x16_bf16(afh, bfw, acc2[m], 0, 0, 0);
      }
    }
    __syncthreads();  // all reads done before next chunk overwrite
  }

  // ---- epilogue: direct coalesced f32 stores ----
  {
    const int cB = wc * 32 + la31;
    const float b3v = b3[cB];
#pragma unroll
    for (int m = 0; m < 2; ++m)
#pragma unroll
      for (int reg = 0; reg < 16; ++reg) {
        const int row = m0 + wr * 64 + m * 32 + (reg & 3) + 8 * (reg >> 2) + 4 * hi;
        out[(size_t)row * 128 + cB] = fmaxf(acc2[m][reg] + b3v, 0.f);
      }
  }
}

extern "C" void kernel_launch(void* const* d_in, const int* in_sizes, int n_in,
                              void* d_out, int out_size, void* d_ws, size_t ws_size,
                              hipStream_t stream) {
  const float* X0 = (const float*)d_in[0];
  const float* Xs = (const float*)d_in[1];
  const float* Wq = (const float*)d_in[2];
  const float* bq = (const float*)d_in[3];
  const float* Wk = (const float*)d_in[4];
  const float* bk = (const float*)d_in[5];
  const float* Wv = (const float*)d_in[6];
  const float* bv = (const float*)d_in[7];
  const float* gp = (const float*)d_in[8];
  const float* W1 = (const float*)d_in[9];
  const float* b1 = (const float*)d_in[10];
  const float* W2 = (const float*)d_in[11];
  const float* b2 = (const float*)d_in[12];
  const float* W3 = (const float*)d_in[13];
  const float* b3 = (const float*)d_in[14];

  char* ws = (char*)d_ws;
  float* Cws = (float*)(ws);                              //   4 KB
  float* Wws = (float*)(ws + 4096);                       // 256 KB
  float* Pws = (float*)(ws + 266240);                     //   1 MB
  float* Rws = (float*)(ws + 1314816);                    //   1 MB
  unsigned short* W2T = (unsigned short*)(ws + 2363392);  //   1 MB (bf16)
  unsigned short* W3T = (unsigned short*)(ws + 3411968);  // 128 KB (bf16)
  float* V0ws = (float*)(ws + 3543040);                   // 512 KB
  float* QKws = (float*)(ws + 4067328);                   // 128 KB
  float* out = (float*)d_out;

  hipLaunchKernelGGL(prep1_k, dim3(656), dim3(256), 0, stream,
                     W2, W3, W2T, W3T, X0, Wv, Wq, Wk, V0ws, QKws);
  hipLaunchKernelGGL(prep2_k, dim3(528), dim3(256), 0, stream,
                     Xs, QKws, bq, Wws, V0ws, X0, bv, W1, gp, b1, Pws, Rws, Cws);
  hipLaunchKernelGGL(fused_k, dim3(512), dim3(512), 0, stream,
                     Xs, gp, W2T, b2, W3T, b3, Cws, Wws, Pws, Rws, out);
}

// Round 9
// 163.252 us; speedup vs baseline: 1.7496x; 1.1057x over previous
//
#include <hip/hip_runtime.h>
#include <hip/hip_bf16.h>

typedef __attribute__((ext_vector_type(8))) short s16x8;
typedef __attribute__((ext_vector_type(16))) float f32x16;

__device__ __forceinline__ unsigned short f2bfu(float x) {
  __hip_bfloat16 b = __float2bfloat16(x);
  return *reinterpret_cast<unsigned short*>(&b);
}
__device__ __forceinline__ short f2bfs(float x) { return (short)f2bfu(x); }

// ======== prep1: pack W2->W2P, W3->W3P (MFMA B-frag order) + xw GEMM ========
// W2P elem index: ((kg*16 + nb)*64 + lane)*8 + j  holds W2[kg*16+(lane>>5)*8+j][nb*32+(lane&31)]
// blocks 0..63: W2P (kg 0..63); 64..95: W3P (kg 0..31); 96..175: xw (80 blocks)
__global__ __launch_bounds__(256) void prep1_k(
    const float* __restrict__ W2, const float* __restrict__ W3,
    unsigned short* __restrict__ W2P, unsigned short* __restrict__ W3P,
    const float* __restrict__ X0, const float* __restrict__ Wv,
    const float* __restrict__ Wq, const float* __restrict__ Wk,
    float* __restrict__ V0ws, float* __restrict__ QKws) {
  const int tid = threadIdx.x;
  if (blockIdx.x < 64) {  // W2 pack
    const int kg = blockIdx.x;
#pragma unroll
    for (int i = 0; i < 4; ++i) {
      const int c = tid + i * 256;          // chunk 0..1023
      const int nb = c >> 6, l = c & 63;
      const int col = nb * 32 + (l & 31);
      const int k0 = kg * 16 + (l >> 5) * 8;
      s16x8 v;
#pragma unroll
      for (int j = 0; j < 8; ++j) v[j] = f2bfs(W2[(size_t)(k0 + j) * 512 + col]);
      *reinterpret_cast<s16x8*>(W2P + ((size_t)kg * 1024 + c) * 8) = v;
    }
    return;
  }
  if (blockIdx.x < 96) {  // W3 pack
    const int kg = blockIdx.x - 64;
    const int c = tid;                      // chunk 0..255
    const int nb = c >> 6, l = c & 63;
    const int col = nb * 32 + (l & 31);
    const int k0 = kg * 16 + (l >> 5) * 8;
    s16x8 v;
#pragma unroll
    for (int j = 0; j < 8; ++j) v[j] = f2bfs(W3[(size_t)(k0 + j) * 128 + col]);
    *reinterpret_cast<s16x8*>(W3P + ((size_t)kg * 256 + c) * 8) = v;
    return;
  }
  // xw part: [V0 | QK] = X0 @ [Wv | Wq | Wk]
  __shared__ float As[32][17];
  __shared__ float Bs[16][68];
  const int r = blockIdx.x - 96;
  const int bn = r % 10, bm = r / 10;
  const int tx = tid & 15, ty = tid >> 4;
  float acc[2][4] = {};
  for (int k0 = 0; k0 < 512; k0 += 16) {
    if (tid < 128) {
      const int row = tid >> 2, kk = (tid & 3) * 4;
      const float4 v = *reinterpret_cast<const float4*>(X0 + (size_t)(bm * 32 + row) * 512 + k0 + kk);
      As[row][kk] = v.x; As[row][kk + 1] = v.y; As[row][kk + 2] = v.z; As[row][kk + 3] = v.w;
    }
    {
      const int k = tid >> 4, n4 = (tid & 15) * 4;
      float4 v;
      if (bn < 8)       v = *reinterpret_cast<const float4*>(Wv + (size_t)(k0 + k) * 512 + bn * 64 + n4);
      else if (bn == 8) v = *reinterpret_cast<const float4*>(Wq + (size_t)(k0 + k) * 64 + n4);
      else              v = *reinterpret_cast<const float4*>(Wk + (size_t)(k0 + k) * 64 + n4);
      Bs[k][n4] = v.x; Bs[k][n4 + 1] = v.y; Bs[k][n4 + 2] = v.z; Bs[k][n4 + 3] = v.w;
    }
    __syncthreads();
#pragma unroll
    for (int kk = 0; kk < 16; ++kk) {
      float a[2], bb[4];
#pragma unroll
      for (int i = 0; i < 2; ++i) a[i] = As[ty * 2 + i][kk];
#pragma unroll
      for (int j = 0; j < 4; ++j) bb[j] = Bs[kk][tx * 4 + j];
#pragma unroll
      for (int i = 0; i < 2; ++i)
#pragma unroll
        for (int j = 0; j < 4; ++j) acc[i][j] = fmaf(a[i], bb[j], acc[i][j]);
    }
    __syncthreads();
  }
#pragma unroll
  for (int i = 0; i < 2; ++i) {
    const int row = bm * 32 + ty * 2 + i;
#pragma unroll
    for (int j = 0; j < 4; ++j) {
      const int n = tx * 4 + j;
      if (bn < 8)       V0ws[(size_t)row * 512 + bn * 64 + n] = acc[i][j];
      else if (bn == 8) QKws[(size_t)row * 128 + n] = acc[i][j];
      else              QKws[(size_t)row * 128 + 64 + n] = acc[i][j];
    }
  }
}

// ======== prep2: wsm (softmax weights) + prc ([P;R;C] GEMM) =====
__global__ __launch_bounds__(256) void prep2_k(
    const float* __restrict__ Xs, const float* __restrict__ QKws,
    const float* __restrict__ bq, float* __restrict__ Wws,
    const float* __restrict__ V0ws, const float* __restrict__ X0,
    const float* __restrict__ bv, const float* __restrict__ W1,
    const float* __restrict__ gp, const float* __restrict__ b1,
    float* __restrict__ Pws, float* __restrict__ Rws, float* __restrict__ Cws) {
  const int tid = threadIdx.x;
  if (blockIdx.x < 256) {
    const int b = blockIdx.x, t = tid;
    __shared__ float sv[256];
    __shared__ float scal[4];
    sv[t] = (t == 0) ? 1.0f : Xs[b * 255 + t - 1];
    __syncthreads();
    if (t == 0) {
      float al = 0, g2 = 0;
      for (int j = 0; j < 64; ++j) {
        al = fmaf(QKws[b * 128 + j], QKws[b * 128 + 64 + j], al);
        g2 = fmaf(bq[j], QKws[b * 128 + 64 + j], g2);
      }
      float mx = sv[0], mn = sv[0];
      for (int m2 = 1; m2 < 256; ++m2) { mx = fmaxf(mx, sv[m2]); mn = fminf(mn, sv[m2]); }
      scal[0] = al; scal[1] = g2; scal[2] = mx; scal[3] = mn;
    }
    __syncthreads();
    const float c = fmaf(scal[0], sv[t], scal[1]);
    const float M = (c >= 0.f) ? c * scal[2] : c * scal[3];
    float Z = 0, Wm = 0;
    for (int m2 = 0; m2 < 256; ++m2) {
      const float e = __expf(fmaf(c, sv[m2], -M));
      Z += e;
      Wm = fmaf(sv[m2], e, Wm);
    }
    Wws[b * 256 + t] = Wm / Z;
    return;
  }
  __shared__ float As[32][17];
  __shared__ float Bs[16][68];
  const int r = blockIdx.x - 256;
  const int bnx = r % 16, bmy = r / 16;
  const int tx = tid & 15, ty = tid >> 4;
  float acc[2][4] = {};
  for (int k0 = 0; k0 < 512; k0 += 16) {
    if (tid < 128) {
      const int row = tid >> 2, kk = (tid & 3) * 4;
      const int rowg = bmy * 32 + row;
      float4 v = {0.f, 0.f, 0.f, 0.f};
      if (rowg < 256)       v = *reinterpret_cast<const float4*>(V0ws + (size_t)rowg * 512 + k0 + kk);
      else if (rowg < 512)  v = *reinterpret_cast<const float4*>(X0 + (size_t)(rowg - 256) * 512 + k0 + kk);
      else if (rowg == 512) v = *reinterpret_cast<const float4*>(bv + k0 + kk);
      As[row][kk] = v.x; As[row][kk + 1] = v.y; As[row][kk + 2] = v.z; As[row][kk + 3] = v.w;
    }
    {
      const int k = tid >> 4, n4 = (tid & 15) * 4;
      const float4 v = *reinterpret_cast<const float4*>(W1 + (size_t)(k0 + k) * 1024 + bnx * 64 + n4);
      Bs[k][n4] = v.x; Bs[k][n4 + 1] = v.y; Bs[k][n4 + 2] = v.z; Bs[k][n4 + 3] = v.w;
    }
    __syncthreads();
#pragma unroll
    for (int kk = 0; kk < 16; ++kk) {
      float a[2], bb[4];
#pragma unroll
      for (int i = 0; i < 2; ++i) a[i] = As[ty * 2 + i][kk];
#pragma unroll
      for (int j = 0; j < 4; ++j) bb[j] = Bs[kk][tx * 4 + j];
#pragma unroll
      for (int i = 0; i < 2; ++i)
#pragma unroll
        for (int j = 0; j < 4; ++j) acc[i][j] = fmaf(a[i], bb[j], acc[i][j]);
    }
    __syncthreads();
  }
  const float g = gp[0];
#pragma unroll
  for (int i = 0; i < 2; ++i) {
    const int rowg = bmy * 32 + ty * 2 + i;
#pragma unroll
    for (int j = 0; j < 4; ++j) {
      const int col = bnx * 64 + tx * 4 + j;
      if (rowg < 256)       Pws[(size_t)rowg * 1024 + col] = acc[i][j];
      else if (rowg < 512)  Rws[(size_t)(rowg - 256) * 1024 + col] = acc[i][j];
      else if (rowg == 512) Cws[col] = fmaf(g, acc[i][j], b1[col]);
    }
  }
}

// ======== fused: out = relu(relu(h1@W2+b2)@W3 + b3), barrier-free K-loop ====
// 512 thr (8 waves 2m x 4n), grid 512 (m0 = bid*128).
// Phase A: wave tile 64x128 (2x4 frags 32x32x16), K=1024 as 64 kg-groups of 16;
//   B-frags = coalesced 1KB loads from pre-packed W2P, pipelined 1 kg ahead
//   in registers; A generated in registers from rank-2 (PRC in LDS). NO
//   barriers in the loop.
// LDS: h2t 128KB [0,131072) (row r at r*1024B, k-oct s at slot (s&56)|((s^r)&7));
//      PRC f32 12KB [131072,143360).
// Phase B: A from h2t (LDS), B from W3P (global, pipelined), direct f32 stores.
__global__ __launch_bounds__(512, 2) void fused_k(
    const float* __restrict__ Xs, const float* __restrict__ gp,
    const unsigned short* __restrict__ W2P,  // packed, 1MB
    const float* __restrict__ b2,
    const unsigned short* __restrict__ W3P,  // packed, 128KB
    const float* __restrict__ b3,
    const float* __restrict__ Cws, const float* __restrict__ Wws,
    const float* __restrict__ Pws, const float* __restrict__ Rws,
    float* __restrict__ out)  // [65536][128] f32
{
  __shared__ __align__(16) unsigned char sm[143360];
  unsigned short* smU = (unsigned short*)sm;
  float* PRC = (float*)(sm + 131072);  // P[1024] | R[1024] | C[1024]
  const int tid = threadIdx.x;
  const int lane = tid & 63, wid = tid >> 6;
  const int la31 = lane & 31, hi = lane >> 5;
  const int wr = wid >> 2, wc = wid & 3;  // 2m x 4n
  const int m0 = blockIdx.x * 128;
  const int b = m0 >> 8;
  const float g = gp[0];

  float gwm[2], srm[2];
#pragma unroll
  for (int m = 0; m < 2; ++m) {
    const int tok = (m0 & 255) + wr * 64 + m * 32 + la31;
    gwm[m] = g * Wws[b * 256 + tok];
    srm[m] = (tok == 0) ? 1.0f : Xs[b * 255 + tok - 1];
  }

  // PRC -> LDS
#pragma unroll
  for (int i = 0; i < 6; ++i) {
    const int idx = i * 512 + tid;
    float v;
    if (idx < 1024)      v = Pws[b * 1024 + idx];
    else if (idx < 2048) v = Rws[b * 1024 + (idx - 1024)];
    else                 v = Cws[idx - 2048];
    PRC[idx] = v;
  }

  f32x16 acc[2][4];
#pragma unroll
  for (int m = 0; m < 2; ++m)
#pragma unroll
    for (int n = 0; n < 4; ++n)
#pragma unroll
      for (int i = 0; i < 16; ++i) acc[m][n][i] = 0.f;

  s16x8 bst[2][4];
  // prologue: load kg=0 B-frags (coalesced 1KB per frag)
#pragma unroll
  for (int nf = 0; nf < 4; ++nf)
    bst[0][nf] = *reinterpret_cast<const s16x8*>(
        W2P + (((0 * 16 + wc * 4 + nf) * 64 + lane) << 3));
  __syncthreads();  // PRC ready (B loads have no LDS dep)

  // ---- phase A: 64 kg-groups, no barriers ----
#pragma unroll 2
  for (int kg = 0; kg < 64; ++kg) {
    const int par = kg & 1;
    if (kg < 63) {
#pragma unroll
      for (int nf = 0; nf < 4; ++nf)
        bst[par ^ 1][nf] = *reinterpret_cast<const s16x8*>(
            W2P + ((((kg + 1) * 16 + wc * 4 + nf) * 64 + lane) << 3));
    }
    // generate A-frags in registers from rank-2 form
    const int kb = kg * 16 + hi * 8;
    const float4 P0 = *(const float4*)(PRC + kb);
    const float4 P1 = *(const float4*)(PRC + kb + 4);
    const float4 R0 = *(const float4*)(PRC + 1024 + kb);
    const float4 R1 = *(const float4*)(PRC + 1024 + kb + 4);
    const float4 C0 = *(const float4*)(PRC + 2048 + kb);
    const float4 C1 = *(const float4*)(PRC + 2048 + kb + 4);
    s16x8 af[2];
#pragma unroll
    for (int m = 0; m < 2; ++m) {
      const float gw = gwm[m], sr = srm[m];
      s16x8 v;
      v[0] = f2bfs(fmaxf(fmaf(gw, P0.x, fmaf(sr, R0.x, C0.x)), 0.f));
      v[1] = f2bfs(fmaxf(fmaf(gw, P0.y, fmaf(sr, R0.y, C0.y)), 0.f));
      v[2] = f2bfs(fmaxf(fmaf(gw, P0.z, fmaf(sr, R0.z, C0.z)), 0.f));
      v[3] = f2bfs(fmaxf(fmaf(gw, P0.w, fmaf(sr, R0.w, C0.w)), 0.f));
      v[4] = f2bfs(fmaxf(fmaf(gw, P1.x, fmaf(sr, R1.x, C1.x)), 0.f));
      v[5] = f2bfs(fmaxf(fmaf(gw, P1.y, fmaf(sr, R1.y, C1.y)), 0.f));
      v[6] = f2bfs(fmaxf(fmaf(gw, P1.z, fmaf(sr, R1.z, C1.z)), 0.f));
      v[7] = f2bfs(fmaxf(fmaf(gw, P1.w, fmaf(sr, R1.w, C1.w)), 0.f));
      af[m] = v;
    }
#pragma unroll
    for (int nf = 0; nf < 4; ++nf)
#pragma unroll
      for (int m = 0; m < 2; ++m)
        acc[m][nf] = __builtin_amdgcn_mfma_f32_32x32x16_bf16(af[m], bst[par][nf], acc[m][nf], 0, 0, 0);
  }

  // ---- transition: h2 (bias+relu, bf16) -> h2t swizzled ----
#pragma unroll
  for (int nf = 0; nf < 4; ++nf) {
    const int col = wc * 128 + nf * 32 + la31;
    const float bb = b2[col];
    const int sc = col >> 3, c7 = col & 7;
#pragma unroll
    for (int m = 0; m < 2; ++m) {
#pragma unroll
      for (int reg = 0; reg < 16; ++reg) {
        const int row = wr * 64 + m * 32 + (reg & 3) + 8 * (reg >> 2) + 4 * hi;
        const int sp = (sc & 56) | ((sc ^ row) & 7);
        smU[row * 512 + sp * 8 + c7] = f2bfu(fmaxf(acc[m][nf][reg] + bb, 0.f));
      }
    }
  }
  __syncthreads();  // h2t ready

  // ---- phase B: out 128x128 = relu(h2t @ W3 + b3); B pipelined from W3P ----
  f32x16 acc2[2];
#pragma unroll
  for (int m = 0; m < 2; ++m)
#pragma unroll
    for (int i = 0; i < 16; ++i) acc2[m][i] = 0.f;

  s16x8 wst[2];
  wst[0] = *reinterpret_cast<const s16x8*>(W3P + (((0 * 4 + wc) * 64 + lane) << 3));
#pragma unroll 2
  for (int kg = 0; kg < 32; ++kg) {
    const int par = kg & 1;
    if (kg < 31)
      wst[par ^ 1] = *reinterpret_cast<const s16x8*>(
          W3P + ((((kg + 1) * 4 + wc) * 64 + lane) << 3));
    const int s = kg * 2 + hi;  // h2t k-oct
#pragma unroll
    for (int m = 0; m < 2; ++m) {
      const int row = wr * 64 + m * 32 + la31;
      const int sp = (s & 56) | ((s ^ row) & 7);
      const s16x8 afh = *(const s16x8*)(&sm[row * 1024 + (sp << 4)]);
      acc2[m] = __builtin_amdgcn_mfma_f32_32x32x16_bf16(afh, wst[par], acc2[m], 0, 0, 0);
    }
  }

  // ---- epilogue: direct coalesced f32 stores ----
  {
    const int cB = wc * 32 + la31;
    const float b3v = b3[cB];
#pragma unroll
    for (int m = 0; m < 2; ++m)
#pragma unroll
      for (int reg = 0; reg < 16; ++reg) {
        const int row = m0 + wr * 64 + m * 32 + (reg & 3) + 8 * (reg >> 2) + 4 * hi;
        out[(size_t)row * 128 + cB] = fmaxf(acc2[m][reg] + b3v, 0.f);
      }
  }
}

extern "C" void kernel_launch(void* const* d_in, const int* in_sizes, int n_in,
                              void* d_out, int out_size, void* d_ws, size_t ws_size,
                              hipStream_t stream) {
  const float* X0 = (const float*)d_in[0];
  const float* Xs = (const float*)d_in[1];
  const float* Wq = (const float*)d_in[2];
  const float* bq = (const float*)d_in[3];
  const float* Wk = (const float*)d_in[4];
  const float* bk = (const float*)d_in[5];
  const float* Wv = (const float*)d_in[6];
  const float* bv = (const float*)d_in[7];
  const float* gp = (const float*)d_in[8];
  const float* W1 = (const float*)d_in[9];
  const float* b1 = (const float*)d_in[10];
  const float* W2 = (const float*)d_in[11];
  const float* b2 = (const float*)d_in[12];
  const float* W3 = (const float*)d_in[13];
  const float* b3 = (const float*)d_in[14];

  char* ws = (char*)d_ws;
  float* Cws = (float*)(ws);                              //   4 KB
  float* Wws = (float*)(ws + 4096);                       // 256 KB
  float* Pws = (float*)(ws + 266240);                     //   1 MB
  float* Rws = (float*)(ws + 1314816);                    //   1 MB
  unsigned short* W2P = (unsigned short*)(ws + 2363392);  //   1 MB (packed bf16)
  unsigned short* W3P = (unsigned short*)(ws + 3411968);  // 128 KB (packed bf16)
  float* V0ws = (float*)(ws + 3543040);                   // 512 KB
  float* QKws = (float*)(ws + 4067328);                   // 128 KB
  float* out = (float*)d_out;

  hipLaunchKernelGGL(prep1_k, dim3(176), dim3(256), 0, stream,
                     W2, W3, W2P, W3P, X0, Wv, Wq, Wk, V0ws, QKws);
  hipLaunchKernelGGL(prep2_k, dim3(528), dim3(256), 0, stream,
                     Xs, QKws, bq, Wws, V0ws, X0, bv, W1, gp, b1, Pws, Rws, Cws);
  hipLaunchKernelGGL(fused_k, dim3(512), dim3(512), 0, stream,
                     Xs, gp, W2P, b2, W3P, b3, Cws, Wws, Pws, Rws, out);
}